// Round 5
// baseline (860.559 us; speedup 1.0000x reference)
//
#include <hip/hip_runtime.h>

#define N_E   4096
#define E_DIM 256
#define NTOK  32768
#define ZX    4096
#define DECAY 0.99f
#define EPSV  1e-5f
#define TAU   0.25f
#define NJB   32        // N_E / 128 j-blocks

typedef _Float16 half8 __attribute__((ext_vector_type(8)));
typedef __attribute__((ext_vector_type(4))) float f32x4;

__device__ __forceinline__ unsigned short f2h(float x) {
    _Float16 h = (_Float16)x;
    unsigned short u;
    __builtin_memcpy(&u, &h, 2);
    return u;
}
__device__ __forceinline__ float h2f(unsigned short u) {
    _Float16 h;
    __builtin_memcpy(&h, &u, 2);
    return (float)h;
}
__device__ __forceinline__ void gload16(const void* g, void* l) {
    __builtin_amdgcn_global_load_lds(
        (const __attribute__((address_space(1))) char*)g,
        (__attribute__((address_space(3))) char*)l, 16, 0, 0);
}

// ---------------- prep z: (b,c,x) fp32 -> zh/zl [t][c] f16 (hi/lo split) ----------------
__global__ void k_prep_z(const float* __restrict__ z,
                         unsigned short* __restrict__ zh, unsigned short* __restrict__ zl) {
    __shared__ float lt[64][65];
    const int bid = blockIdx.x;
    const int xt = bid & 63, ct = (bid >> 6) & 3, b = bid >> 8;
    const int tid = threadIdx.x;
    #pragma unroll
    for (int r = 0; r < 4; ++r) {
        int cy = r * 16 + (tid >> 4);
        int xx4 = tid & 15;
        float4 v = ((const float4*)z)[(size_t)(b * 256 + ct * 64 + cy) * 1024 + xt * 16 + xx4];
        lt[cy][xx4 * 4 + 0] = v.x; lt[cy][xx4 * 4 + 1] = v.y;
        lt[cy][xx4 * 4 + 2] = v.z; lt[cy][xx4 * 4 + 3] = v.w;
    }
    __syncthreads();
    #pragma unroll
    for (int it = 0; it < 2; ++it) {
        int tl = it * 32 + (tid >> 3);
        int c8 = tid & 7;
        unsigned short h[8], l[8];
        #pragma unroll
        for (int u = 0; u < 8; ++u) {
            float f = lt[c8 * 8 + u][tl];
            h[u] = f2h(f);
            l[u] = f2h(f - h2f(h[u]));
        }
        size_t t = (size_t)(b * 4096 + xt * 64 + tl);
        size_t o = t * 256 + ct * 64 + c8 * 8;
        *(ushort4*)&zh[o]     = make_ushort4(h[0], h[1], h[2], h[3]);
        *(ushort4*)&zh[o + 4] = make_ushort4(h[4], h[5], h[6], h[7]);
        *(ushort4*)&zl[o]     = make_ushort4(l[0], l[1], l[2], l[3]);
        *(ushort4*)&zl[o + 4] = make_ushort4(l[4], l[5], l[6], l[7]);
    }
}

// ---------------- prep emb: Bp = e (f16), enorm32/64; fused init ----------------
__global__ void k_prep_e(const float* __restrict__ emb, unsigned short* __restrict__ Bp,
                         float* __restrict__ enorm32, double* __restrict__ enorm64,
                         int* __restrict__ cnt, int* __restrict__ flagCount) {
    if (threadIdx.x < 4) cnt[blockIdx.x * 4 + threadIdx.x] = 0;
    if (blockIdx.x == 0 && threadIdx.x == 0) *flagCount = 0;
    int j = blockIdx.x * 4 + (threadIdx.x >> 6);
    int lane = threadIdx.x & 63;
    float4 v = ((const float4*)emb)[(size_t)j * 64 + lane];
    float f[4] = {v.x, v.y, v.z, v.w};
    unsigned short h[4];
    #pragma unroll
    for (int u = 0; u < 4; ++u) h[u] = f2h(f[u]);
    *(ushort4*)&Bp[(size_t)j * E_DIM + lane * 4] = make_ushort4(h[0], h[1], h[2], h[3]);
    double s = 0.0;
    #pragma unroll
    for (int u = 0; u < 4; ++u) s += (double)f[u] * (double)f[u];
    #pragma unroll
    for (int off = 32; off; off >>= 1) s += __shfl_down(s, off, 64);
    if (lane == 0) { enorm32[j] = (float)s; enorm64[j] = s; }
}

// ---------------- MFMA f16 distance / top-2 argmin (round-3 structure, K=256) ----------------
__global__ __launch_bounds__(256) void k_dist(
        const unsigned short* __restrict__ zh,
        const unsigned short* __restrict__ Bp, const float* __restrict__ enorm32,
        float* __restrict__ pm1, float* __restrict__ pm2, int* __restrict__ pidx) {
    __shared__ __align__(16) char smem[65536];   // 2 x (16KB A + 16KB B)
    const int tid = threadIdx.x;
    const int lane = tid & 63;
    const int w = tid >> 6;
    const int wr = w >> 1, wc = w & 1;
    const int t0 = blockIdx.x * 128;
    const int jb = blockIdx.y;
    const int j0 = jb * 128;
    // pre-swizzled source byte offset (rule #21): LDS[r][c] holds data[r][c ^ ((r&7)<<4)]
    const int sw16 = (((lane & 7) ^ (lane >> 3)) << 4);
    const int rowsub = lane >> 3;

    f32x4 acc[4][4];
    #pragma unroll
    for (int m = 0; m < 4; ++m)
        #pragma unroll
        for (int nn = 0; nn < 4; ++nn)
            acc[m][nn] = (f32x4){0.f, 0.f, 0.f, 0.f};

    auto stage = [&](int s, int buf) {
        const int kb = s * 128 + sw16;
        char* base = smem + buf * 32768;
        #pragma unroll
        for (int c = 0; c < 4; ++c) {
            int seg = w * 4 + c;
            int arow = t0 + seg * 8 + rowsub;
            int brow = j0 + seg * 8 + rowsub;
            gload16((const char*)zh + (size_t)arow * 512 + kb, base + seg * 1024);
            gload16((const char*)Bp + (size_t)brow * 512 + kb, base + 16384 + seg * 1024);
        }
    };

    stage(0, 0);
    __syncthreads();
    for (int s = 0; s < 4; ++s) {
        const int buf = s & 1;
        if (s < 3) stage(s + 1, buf ^ 1);
        const int xr = ((lane & 7) << 4);        // read-side XOR
        #pragma unroll
        for (int kk = 0; kk < 2; ++kk) {
            const int colb = (kk * 64 + ((lane >> 4) << 4)) ^ xr;
            half8 a[4], b[4];
            #pragma unroll
            for (int m = 0; m < 4; ++m)
                a[m] = *(const half8*)&smem[buf * 32768
                        + ((wr * 64 + m * 16 + (lane & 15)) << 7) + colb];
            #pragma unroll
            for (int nn = 0; nn < 4; ++nn)
                b[nn] = *(const half8*)&smem[buf * 32768 + 16384
                        + ((wc * 64 + nn * 16 + (lane & 15)) << 7) + colb];
            #pragma unroll
            for (int m = 0; m < 4; ++m)
                #pragma unroll
                for (int nn = 0; nn < 4; ++nn)
                    acc[m][nn] = __builtin_amdgcn_mfma_f32_16x16x32_f16(a[m], b[nn], acc[m][nn], 0, 0, 0);
        }
        __syncthreads();
    }

    // epilogue: score = ||e||^2 - 2 z.e ; per-token top-2 over this block's 128 codes
    float bm1[4][4], bm2[4][4]; int bx1[4][4];
    #pragma unroll
    for (int m = 0; m < 4; ++m)
        #pragma unroll
        for (int r = 0; r < 4; ++r) { bm1[m][r] = 3.4e38f; bm2[m][r] = 3.4e38f; bx1[m][r] = 0; }
    #pragma unroll
    for (int nn = 0; nn < 4; ++nn) {
        int j = j0 + wc * 64 + nn * 16 + (lane & 15);
        float en = enorm32[j];
        #pragma unroll
        for (int m = 0; m < 4; ++m)
            #pragma unroll
            for (int r = 0; r < 4; ++r) {
                float sc = fmaf(-2.f, acc[m][nn][r], en);
                if (sc < bm1[m][r]) { bm2[m][r] = bm1[m][r]; bm1[m][r] = sc; bx1[m][r] = j; }
                else if (sc < bm2[m][r]) bm2[m][r] = sc;
            }
    }
    #pragma unroll
    for (int off = 8; off >= 1; off >>= 1) {
        #pragma unroll
        for (int m = 0; m < 4; ++m)
            #pragma unroll
            for (int r = 0; r < 4; ++r) {
                float om1 = __shfl_xor(bm1[m][r], off, 64);
                float om2 = __shfl_xor(bm2[m][r], off, 64);
                int   ox1 = __shfl_xor(bx1[m][r], off, 64);
                bool take = (om1 < bm1[m][r]) || (om1 == bm1[m][r] && ox1 < bx1[m][r]);
                float n2 = take ? fminf(bm1[m][r], om2) : fminf(om1, bm2[m][r]);
                if (take) { bm1[m][r] = om1; bx1[m][r] = ox1; }
                bm2[m][r] = n2;
            }
    }
    // merge the two wc-waves via LDS (tiles dead after final barrier)
    float* mb1 = (float*)smem;            // [2][128]
    float* mb2 = (float*)(smem + 1024);
    int*   mbi = (int*)(smem + 2048);
    if ((lane & 15) == 0) {
        int g = lane >> 4;
        #pragma unroll
        for (int m = 0; m < 4; ++m)
            #pragma unroll
            for (int r = 0; r < 4; ++r) {
                int tl = wr * 64 + m * 16 + g * 4 + r;
                mb1[wc * 128 + tl] = bm1[m][r];
                mb2[wc * 128 + tl] = bm2[m][r];
                mbi[wc * 128 + tl] = bx1[m][r];
            }
    }
    __syncthreads();
    if (tid < 128) {
        float a1 = mb1[tid], a2 = mb2[tid]; int ai = mbi[tid];
        float c1 = mb1[128 + tid], c2 = mb2[128 + tid]; int ci = mbi[128 + tid];
        bool take = (c1 < a1) || (c1 == a1 && ci < ai);
        float m1 = take ? c1 : a1;
        int   x1 = take ? ci : ai;
        float m2 = take ? fminf(a1, c2) : fminf(c1, a2);
        int t = t0 + tid;
        pm1[(size_t)jb * NTOK + t] = m1;
        pm2[(size_t)jb * NTOK + t] = m2;
        pidx[(size_t)jb * NTOK + t] = x1;
    }
}

// ---------------- merge j-blocks, histogram, idx out, flag near-ties ----------------
__global__ void k_merge(const float* __restrict__ pm1, const float* __restrict__ pm2,
                        const int* __restrict__ pidx, int* __restrict__ idx32,
                        int* __restrict__ cnt, float* __restrict__ out_idx,
                        int* __restrict__ flagList, int* __restrict__ flagCount) {
    int t = blockIdx.x * blockDim.x + threadIdx.x;
    if (t >= NTOK) return;
    float m1 = 3.4e38f, m2 = 3.4e38f; int x1 = 0x7fffffff;
    for (int s = 0; s < NJB; s++) {
        float om1 = pm1[(size_t)s * NTOK + t], om2 = pm2[(size_t)s * NTOK + t];
        int ox1 = pidx[(size_t)s * NTOK + t];
        bool take = (om1 < m1) || (om1 == m1 && ox1 < x1);
        float n2 = take ? fminf(m1, om2) : fminf(om1, m2);
        if (take) { m1 = om1; x1 = ox1; }
        m2 = n2;
    }
    idx32[t] = x1;
    atomicAdd(&cnt[x1], 1);
    out_idx[t] = (float)x1;
    if (m2 - m1 < TAU) {
        int p = atomicAdd(flagCount, 1);
        flagList[p] = t;
    }
}

// ---------------- fp64 recheck of flagged tokens (patches idx/cnt/out_idx) ----------------
__global__ void k_recheck(const float* __restrict__ z, const float* __restrict__ emb,
                          const double* __restrict__ enorm64,
                          const int* __restrict__ flagList, const int* __restrict__ flagCount,
                          int* __restrict__ idx32, int* __restrict__ cnt,
                          float* __restrict__ out_idx) {
    __shared__ float zrow[E_DIM];
    __shared__ double rv[1024];
    __shared__ int ri[1024];
    const int tid = threadIdx.x;
    const int nf = *flagCount;
    for (int f = blockIdx.x; f < nf; f += gridDim.x) {
        const int t = flagList[f];
        const int b = t >> 12, x = t & 4095;
        __syncthreads();
        if (tid < E_DIM) zrow[tid] = z[(size_t)(b * 256 + tid) * 4096 + x];
        __syncthreads();
        double best = 1e300; int bi = 0x7fffffff;
        for (int s = 0; s < N_E / 1024; s++) {
            int j = s * 1024 + tid;
            const float* er = emb + (size_t)j * E_DIM;
            double a0 = 0.0, a1 = 0.0, a2 = 0.0, a3 = 0.0;
            for (int k = 0; k < E_DIM; k += 4) {
                a0 = fma((double)er[k + 0], (double)zrow[k + 0], a0);
                a1 = fma((double)er[k + 1], (double)zrow[k + 1], a1);
                a2 = fma((double)er[k + 2], (double)zrow[k + 2], a2);
                a3 = fma((double)er[k + 3], (double)zrow[k + 3], a3);
            }
            double d = enorm64[j] - 2.0 * ((a0 + a1) + (a2 + a3));
            if (d < best || (d == best && j < bi)) { best = d; bi = j; }
        }
        rv[tid] = best; ri[tid] = bi;
        __syncthreads();
        for (int off = 512; off; off >>= 1) {
            if (tid < off) {
                if (rv[tid + off] < rv[tid] ||
                    (rv[tid + off] == rv[tid] && ri[tid + off] < ri[tid])) {
                    rv[tid] = rv[tid + off]; ri[tid] = ri[tid + off];
                }
            }
            __syncthreads();
        }
        if (tid == 0) {
            int old = idx32[t];
            int nw = ri[0];
            if (nw != old) {
                idx32[t] = nw;
                out_idx[t] = (float)nw;
                atomicSub(&cnt[old], 1);
                atomicAdd(&cnt[nw], 1);
            }
        }
        __syncthreads();
    }
}

// ---------------- exclusive scan of cnt[4096] + n/usage stats ----------------
__global__ void k_scan(const int* __restrict__ cnt, int* __restrict__ offs,
                       const float* __restrict__ cluster_size,
                       float* __restrict__ nval, float* __restrict__ out_usage) {
    __shared__ int sc[1024];
    __shared__ float sn[1024];
    __shared__ float su[1024];
    int tid = threadIdx.x;
    int c0 = cnt[tid * 4], c1 = cnt[tid * 4 + 1], c2 = cnt[tid * 4 + 2], c3 = cnt[tid * 4 + 3];
    int ls = c0 + c1 + c2 + c3;
    float ns = 0.f, us = 0.f;
    {
        int cc[4] = {c0, c1, c2, c3};
        #pragma unroll
        for (int u = 0; u < 4; ++u) {
            ns += cluster_size[tid * 4 + u] * DECAY + (1.f - DECAY) * (float)cc[u];
            us += (cc[u] > 0) ? 1.f : 0.f;
        }
    }
    sc[tid] = ls; sn[tid] = ns; su[tid] = us;
    __syncthreads();
    for (int off = 1; off < 1024; off <<= 1) {
        int v = (tid >= off) ? sc[tid - off] : 0;
        __syncthreads();
        sc[tid] += v;
        __syncthreads();
    }
    int base = sc[tid] - ls;
    offs[tid * 4] = base;
    offs[tid * 4 + 1] = base + c0;
    offs[tid * 4 + 2] = base + c0 + c1;
    offs[tid * 4 + 3] = base + c0 + c1 + c2;
    for (int off = 512; off; off >>= 1) {
        if (tid < off) { sn[tid] += sn[tid + off]; su[tid] += su[tid + off]; }
        __syncthreads();
    }
    if (tid == 0) { *nval = sn[0]; *out_usage = su[0] / (float)N_E; }
}

// ---------------- place tokens into per-code lists ----------------
__global__ void k_place(const int* __restrict__ idx32, int* __restrict__ offs,
                        int* __restrict__ tokList) {
    int t = blockIdx.x * blockDim.x + threadIdx.x;
    if (t >= NTOK) return;
    int j = idx32[t];
    int p = atomicAdd(&offs[j], 1);
    tokList[p] = t;
}

// ---------------- dw: per-code coalesced reduction, 4 lane-groups ----------------
__global__ void k_dw(const unsigned short* __restrict__ zh, const unsigned short* __restrict__ zl,
                     const int* __restrict__ cnt, const int* __restrict__ offs,
                     const int* __restrict__ tokList, float* __restrict__ dw) {
    __shared__ float red[4][256];
    int j = blockIdx.x;
    int g = threadIdx.x >> 6;
    int lane = threadIdx.x & 63;
    int n = cnt[j];
    int s0 = offs[j] - n;     // offs holds end positions after k_place
    float4 acc = make_float4(0.f, 0.f, 0.f, 0.f);
    for (int i = g; i < n; i += 4) {
        int t = tokList[s0 + i];
        ushort4 h = *(const ushort4*)&zh[(size_t)t * 256 + lane * 4];
        ushort4 l = *(const ushort4*)&zl[(size_t)t * 256 + lane * 4];
        acc.x += h2f(h.x) + h2f(l.x);
        acc.y += h2f(h.y) + h2f(l.y);
        acc.z += h2f(h.z) + h2f(l.z);
        acc.w += h2f(h.w) + h2f(l.w);
    }
    red[g][lane * 4 + 0] = acc.x; red[g][lane * 4 + 1] = acc.y;
    red[g][lane * 4 + 2] = acc.z; red[g][lane * 4 + 3] = acc.w;
    __syncthreads();
    if (g == 0) {
        #pragma unroll
        for (int u = 0; u < 4; ++u) {
            int c = lane * 4 + u;
            dw[(size_t)j * 256 + c] = red[0][c] + red[1][c] + red[2][c] + red[3][c];
        }
    }
}

// ---------------- zq gather ----------------
__global__ void k_zq(const float* __restrict__ emb, const int* __restrict__ idx32,
                     float* __restrict__ out_zq) {
    int t = blockIdx.x * blockDim.x + threadIdx.x;
    int j = idx32[t];
    int b = t >> 12, x = t & 4095;
    const float4* er = (const float4*)(emb + (size_t)j * E_DIM);
    float* ob = out_zq + (size_t)b * (E_DIM * ZX) + x;
    #pragma unroll 8
    for (int c4 = 0; c4 < E_DIM / 4; c4++) {
        float4 v = er[c4];
        ob[(size_t)(c4 * 4 + 0) * ZX] = v.x;
        ob[(size_t)(c4 * 4 + 1) * ZX] = v.y;
        ob[(size_t)(c4 * 4 + 2) * ZX] = v.z;
        ob[(size_t)(c4 * 4 + 3) * ZX] = v.w;
    }
}

// ---------------- EMA epilogue ----------------
__global__ void k_final(const float* __restrict__ cluster_size, const int* __restrict__ cnt,
                        const float* __restrict__ emb_avg, const float* __restrict__ dw,
                        const float* __restrict__ nval,
                        float* __restrict__ out_cluster, float* __restrict__ out_avg,
                        float* __restrict__ out_embed) {
    int j = blockIdx.x;
    int k = threadIdx.x;
    float nc = cluster_size[j] * DECAY + (1.f - DECAY) * (float)cnt[j];
    float n = *nval;
    float cs = (nc + EPSV) / (n + (float)N_E * EPSV) * n;
    float na = emb_avg[(size_t)j * E_DIM + k] * DECAY + (1.f - DECAY) * dw[(size_t)j * E_DIM + k];
    out_avg[(size_t)j * E_DIM + k] = na;
    out_embed[(size_t)j * E_DIM + k] = na / cs;
    if (k == 0) out_cluster[j] = nc;
}

extern "C" void kernel_launch(void* const* d_in, const int* in_sizes, int n_in,
                              void* d_out, int out_size, void* d_ws, size_t ws_size,
                              hipStream_t stream) {
    const float* z            = (const float*)d_in[0];
    const float* emb          = (const float*)d_in[1];
    const float* cluster_size = (const float*)d_in[2];
    const float* emb_avg      = (const float*)d_in[3];
    float* out = (float*)d_out;

    // ---- d_ws layout (bytes), total ~34 MB ----
    char* ws = (char*)d_ws;
    unsigned short* zh   = (unsigned short*)(ws + 0);          // 16,777,216 (f16 hi)
    unsigned short* zl   = (unsigned short*)(ws + 16777216);   // 16,777,216 (f16 lo)
    float* enorm32       = (float*)(ws + 33554432);            // 16,384
    double* enorm64      = (double*)(ws + 33570816);           // 32,768
    int* idx32           = (int*)(ws + 33603584);              // 131,072
    int* flagList        = (int*)(ws + 33734656);              // 131,072
    int* cnt             = (int*)(ws + 33865728);              // 16,384
    int* offs            = (int*)(ws + 33882112);              // 16,384
    int* flagCnt         = (int*)(ws + 33898496);              // 64
    float* nval          = (float*)(ws + 33898560);            // 64

    // ---- scratch inside d_out's zq region (written last by k_zq) ----
    float* pm1           = out + 0;                 // 1,048,576 f
    float* pm2           = out + 1048576;           // 1,048,576 f
    int*   pidx          = (int*)(out + 2097152);   // 1,048,576 i
    float* dw            = out + 3145728;           // 1,048,576 f
    unsigned short* Bp   = (unsigned short*)(out + 4194304);   // 2,097,152 B (f16 emb)
    int*   tokList       = (int*)(out + 5767168);   // 32,768 i

    // ---- output sections ----
    float* out_zq      = out + 0;
    float* out_idx     = out + 8388608;
    float* out_cluster = out + 8421376;
    float* out_avg     = out + 8425472;
    float* out_embed   = out + 9474048;
    float* out_usage   = out + 10522624;

    hipLaunchKernelGGL(k_prep_z, dim3(2048), dim3(256), 0, stream, z, zh, zl);
    hipLaunchKernelGGL(k_prep_e, dim3(1024), dim3(256), 0, stream, emb, Bp, enorm32, enorm64,
                       cnt, flagCnt);
    hipLaunchKernelGGL(k_dist,   dim3(256, NJB), dim3(256), 0, stream,
                       zh, Bp, enorm32, pm1, pm2, pidx);
    hipLaunchKernelGGL(k_merge,  dim3(128), dim3(256), 0, stream,
                       pm1, pm2, pidx, idx32, cnt, out_idx, flagList, flagCnt);
    hipLaunchKernelGGL(k_recheck, dim3(512), dim3(1024), 0, stream,
                       z, emb, enorm64, flagList, flagCnt, idx32, cnt, out_idx);
    hipLaunchKernelGGL(k_scan,   dim3(1), dim3(1024), 0, stream, cnt, offs,
                       cluster_size, nval, out_usage);
    hipLaunchKernelGGL(k_place,  dim3(128), dim3(256), 0, stream, idx32, offs, tokList);
    hipLaunchKernelGGL(k_dw,     dim3(4096), dim3(256), 0, stream, zh, zl, cnt, offs, tokList, dw);
    hipLaunchKernelGGL(k_final,  dim3(4096), dim3(256), 0, stream,
                       cluster_size, cnt, emb_avg, dw, nval,
                       out_cluster, out_avg, out_embed);
    hipLaunchKernelGGL(k_zq,     dim3(128), dim3(256), 0, stream, emb, idx32, out_zq);
}

// Round 6
// 782.500 us; speedup vs baseline: 1.0998x; 1.0998x over previous
//
#include <hip/hip_runtime.h>

#define N_E   4096
#define E_DIM 256
#define NTOK  32768
#define ZX    4096
#define DECAY 0.99f
#define EPSV  1e-5f
#define TAU   0.25f
#define NJB   32        // N_E / 128 j-blocks
#define IBIG  0x7fffffff

typedef _Float16 half8 __attribute__((ext_vector_type(8)));
typedef __attribute__((ext_vector_type(4))) float f32x4;

__device__ __forceinline__ unsigned short f2h(float x) {
    _Float16 h = (_Float16)x;
    unsigned short u;
    __builtin_memcpy(&u, &h, 2);
    return u;
}
__device__ __forceinline__ float h2f(unsigned short u) {
    _Float16 h;
    __builtin_memcpy(&h, &u, 2);
    return (float)h;
}
__device__ __forceinline__ bool flt(float v, int i, float w, int j) {
    return v < w || (v == w && i < j);
}
__device__ __forceinline__ void gload16(const void* g, void* l) {
    __builtin_amdgcn_global_load_lds(
        (const __attribute__((address_space(1))) char*)g,
        (__attribute__((address_space(3))) char*)l, 16, 0, 0);
}

// ---------------- prep z: (b,c,x) fp32 -> zh [t][c] f16 ----------------
__global__ void k_prep_z(const float* __restrict__ z, unsigned short* __restrict__ zh) {
    __shared__ float lt[64][65];
    const int bid = blockIdx.x;
    const int xt = bid & 63, ct = (bid >> 6) & 3, b = bid >> 8;
    const int tid = threadIdx.x;
    #pragma unroll
    for (int r = 0; r < 4; ++r) {
        int cy = r * 16 + (tid >> 4);
        int xx4 = tid & 15;
        float4 v = ((const float4*)z)[(size_t)(b * 256 + ct * 64 + cy) * 1024 + xt * 16 + xx4];
        lt[cy][xx4 * 4 + 0] = v.x; lt[cy][xx4 * 4 + 1] = v.y;
        lt[cy][xx4 * 4 + 2] = v.z; lt[cy][xx4 * 4 + 3] = v.w;
    }
    __syncthreads();
    #pragma unroll
    for (int it = 0; it < 2; ++it) {
        int tl = it * 32 + (tid >> 3);
        int c8 = tid & 7;
        unsigned short h[8];
        #pragma unroll
        for (int u = 0; u < 8; ++u) h[u] = f2h(lt[c8 * 8 + u][tl]);
        size_t t = (size_t)(b * 4096 + xt * 64 + tl);
        size_t o = t * 256 + ct * 64 + c8 * 8;
        *(ushort4*)&zh[o]     = make_ushort4(h[0], h[1], h[2], h[3]);
        *(ushort4*)&zh[o + 4] = make_ushort4(h[4], h[5], h[6], h[7]);
    }
}

// ---------------- prep emb: Bp = e (f16), enorm32/64; fused init ----------------
__global__ void k_prep_e(const float* __restrict__ emb, unsigned short* __restrict__ Bp,
                         float* __restrict__ enorm32, double* __restrict__ enorm64,
                         int* __restrict__ cnt, int* __restrict__ flagCnt,
                         int* __restrict__ flagCnt2) {
    if (threadIdx.x < 4) cnt[blockIdx.x * 4 + threadIdx.x] = 0;
    if (blockIdx.x == 0 && threadIdx.x == 0) { *flagCnt = 0; *flagCnt2 = 0; }
    int j = blockIdx.x * 4 + (threadIdx.x >> 6);
    int lane = threadIdx.x & 63;
    float4 v = ((const float4*)emb)[(size_t)j * 64 + lane];
    float f[4] = {v.x, v.y, v.z, v.w};
    unsigned short h[4];
    #pragma unroll
    for (int u = 0; u < 4; ++u) h[u] = f2h(f[u]);
    *(ushort4*)&Bp[(size_t)j * E_DIM + lane * 4] = make_ushort4(h[0], h[1], h[2], h[3]);
    double s = 0.0;
    #pragma unroll
    for (int u = 0; u < 4; ++u) s += (double)f[u] * (double)f[u];
    #pragma unroll
    for (int off = 32; off; off >>= 1) s += __shfl_down(s, off, 64);
    if (lane == 0) { enorm32[j] = (float)s; enorm64[j] = s; }
}

// ---------------- MFMA f16 distance, top-4 per token per j-block ----------------
__global__ __launch_bounds__(256) void k_dist(
        const unsigned short* __restrict__ zh,
        const unsigned short* __restrict__ Bp, const float* __restrict__ enorm32,
        float* __restrict__ pm1, float* __restrict__ pm2, float* __restrict__ pm3,
        float* __restrict__ pm4, int* __restrict__ pxA, int* __restrict__ pxB) {
    __shared__ __align__(16) char smem[65536];   // dbuf tiles; reused for C-stage
    const int tid = threadIdx.x;
    const int lane = tid & 63;
    const int w = tid >> 6;
    const int wr = w >> 1, wc = w & 1;
    const int t0 = blockIdx.x * 128;
    const int jb = blockIdx.y;
    const int j0 = jb * 128;
    const int sw16 = (((lane & 7) ^ (lane >> 3)) << 4);
    const int rowsub = lane >> 3;

    f32x4 acc[4][4];
    #pragma unroll
    for (int m = 0; m < 4; ++m)
        #pragma unroll
        for (int nn = 0; nn < 4; ++nn)
            acc[m][nn] = (f32x4){0.f, 0.f, 0.f, 0.f};

    auto stage = [&](int s, int buf) {
        const int kb = s * 128 + sw16;
        char* base = smem + buf * 32768;
        #pragma unroll
        for (int c = 0; c < 4; ++c) {
            int seg = w * 4 + c;
            int arow = t0 + seg * 8 + rowsub;
            int brow = j0 + seg * 8 + rowsub;
            gload16((const char*)zh + (size_t)arow * 512 + kb, base + seg * 1024);
            gload16((const char*)Bp + (size_t)brow * 512 + kb, base + 16384 + seg * 1024);
        }
    };

    stage(0, 0);
    __syncthreads();
    for (int s = 0; s < 4; ++s) {
        const int buf = s & 1;
        if (s < 3) stage(s + 1, buf ^ 1);
        const int xr = ((lane & 7) << 4);
        #pragma unroll
        for (int kk = 0; kk < 2; ++kk) {
            const int colb = (kk * 64 + ((lane >> 4) << 4)) ^ xr;
            half8 a[4], b[4];
            #pragma unroll
            for (int m = 0; m < 4; ++m)
                a[m] = *(const half8*)&smem[buf * 32768
                        + ((wr * 64 + m * 16 + (lane & 15)) << 7) + colb];
            #pragma unroll
            for (int nn = 0; nn < 4; ++nn)
                b[nn] = *(const half8*)&smem[buf * 32768 + 16384
                        + ((wc * 64 + nn * 16 + (lane & 15)) << 7) + colb];
            #pragma unroll
            for (int m = 0; m < 4; ++m)
                #pragma unroll
                for (int nn = 0; nn < 4; ++nn)
                    acc[m][nn] = __builtin_amdgcn_mfma_f32_16x16x32_f16(a[m], b[nn], acc[m][nn], 0, 0, 0);
        }
        __syncthreads();
    }

    // ---- epilogue: stage scores in LDS per 64-col half; 128 threads scan top-4 ----
    float* Ch = (float*)smem;                 // [128][65] f32
    const int c0 = lane & 15;
    const int g  = lane >> 4;
    float en[4];
    #pragma unroll
    for (int nn = 0; nn < 4; ++nn) en[nn] = enorm32[j0 + wc * 64 + nn * 16 + c0];

    float m1 = 3.4e38f, m2 = 3.4e38f, m3 = 3.4e38f, m4 = 3.4e38f;
    int x1 = IBIG, x2 = IBIG, x3 = IBIG;

    #pragma unroll
    for (int h = 0; h < 2; ++h) {
        __syncthreads();
        if (wc == h) {
            #pragma unroll
            for (int m = 0; m < 4; ++m)
                #pragma unroll
                for (int nn = 0; nn < 4; ++nn)
                    #pragma unroll
                    for (int r = 0; r < 4; ++r) {
                        int tl = wr * 64 + m * 16 + g * 4 + r;
                        Ch[tl * 65 + nn * 16 + c0] = fmaf(-2.f, acc[m][nn][r], en[nn]);
                    }
        }
        __syncthreads();
        if (tid < 128) {
            const int jb0 = j0 + h * 64;
            const float* row = &Ch[tid * 65];
            for (int c = 0; c < 64; ++c) {
                float v = row[c];
                if (v < m4) {
                    int j = jb0 + c;
                    if (flt(v, j, m1, x1))      { m4 = m3; m3 = m2; x3 = x2; m2 = m1; x2 = x1; m1 = v; x1 = j; }
                    else if (flt(v, j, m2, x2)) { m4 = m3; m3 = m2; x3 = x2; m2 = v; x2 = j; }
                    else if (flt(v, j, m3, x3)) { m4 = m3; m3 = v; x3 = j; }
                    else                        { m4 = v; }
                }
            }
        }
    }
    if (tid < 128) {
        size_t o = (size_t)jb * NTOK + t0 + tid;
        pm1[o] = m1; pm2[o] = m2; pm3[o] = m3; pm4[o] = m4;
        pxA[o] = (x1 & 0xffff) | (x2 << 16);
        pxB[o] = x3;
    }
}

// ---------------- merge j-blocks (top-4), histogram, idx out, tiered flags ----------------
__global__ void k_merge(const float* __restrict__ pm1, const float* __restrict__ pm2,
                        const float* __restrict__ pm3, const float* __restrict__ pm4,
                        const int* __restrict__ pxA, const int* __restrict__ pxB,
                        int* __restrict__ idx32, int* __restrict__ cnt,
                        float* __restrict__ out_idx, int* __restrict__ xpair,
                        int* __restrict__ flagList, int* __restrict__ flagCount,
                        int* __restrict__ flagList2, int* __restrict__ flagCount2) {
    int t = blockIdx.x * blockDim.x + threadIdx.x;
    if (t >= NTOK) return;
    float m1 = 3.4e38f, m2 = 3.4e38f, m3 = 3.4e38f, m4 = 3.4e38f;
    int x1 = IBIG, x2 = IBIG, x3 = IBIG;
    auto ins = [&](float v, int j) {
        if (v < m4) {
            if (flt(v, j, m1, x1))      { m4 = m3; m3 = m2; x3 = x2; m2 = m1; x2 = x1; m1 = v; x1 = j; }
            else if (flt(v, j, m2, x2)) { m4 = m3; m3 = m2; x3 = x2; m2 = v; x2 = j; }
            else if (flt(v, j, m3, x3)) { m4 = m3; m3 = v; x3 = j; }
            else                        { m4 = v; }
        }
    };
    for (int s = 0; s < NJB; s++) {
        size_t o = (size_t)s * NTOK + t;
        int a = pxA[o], b = pxB[o];
        ins(pm1[o], a & 0xffff);
        ins(pm2[o], (a >> 16) & 0xffff);
        ins(pm3[o], b);
        ins(pm4[o], IBIG);
    }
    idx32[t] = x1;
    atomicAdd(&cnt[x1], 1);
    out_idx[t] = (float)x1;
    if (m4 - m1 < TAU) {
        int p = atomicAdd(flagCount2, 1);
        flagList2[p] = t;
    } else if (m2 - m1 < TAU) {
        xpair[t] = (x2 & 0xffff) | (x3 << 16);
        int p = atomicAdd(flagCount, 1);
        flagList[p] = t;
    }
}

// ---------------- exact fp64 compare of {x1,x2,x3} for tri-flagged tokens ----------------
__global__ void k_tri(const float* __restrict__ z, const float* __restrict__ emb,
                      const double* __restrict__ enorm64,
                      const int* __restrict__ flagList, const int* __restrict__ flagCount,
                      const int* __restrict__ xpair,
                      int* __restrict__ idx32, int* __restrict__ cnt,
                      float* __restrict__ out_idx) {
    const int lane = threadIdx.x & 63;
    const int wid = blockIdx.x * (blockDim.x >> 6) + (threadIdx.x >> 6);
    const int nw = gridDim.x * (blockDim.x >> 6);
    const int nf = *flagCount;
    for (int f = wid; f < nf; f += nw) {
        int t = flagList[f];
        int b = t >> 12, x = t & 4095;
        int x1 = idx32[t];
        int xp = xpair[t];
        int x2 = xp & 0xffff, x3 = (xp >> 16) & 0xffff;
        double zz[4];
        #pragma unroll
        for (int u = 0; u < 4; ++u)
            zz[u] = (double)z[(size_t)(b * 256 + lane * 4 + u) * 4096 + x];
        float4 e1 = ((const float4*)emb)[(size_t)x1 * 64 + lane];
        float4 e2 = ((const float4*)emb)[(size_t)x2 * 64 + lane];
        float4 e3 = ((const float4*)emb)[(size_t)x3 * 64 + lane];
        double d1 = zz[0] * (double)e1.x + zz[1] * (double)e1.y + zz[2] * (double)e1.z + zz[3] * (double)e1.w;
        double d2 = zz[0] * (double)e2.x + zz[1] * (double)e2.y + zz[2] * (double)e2.z + zz[3] * (double)e2.w;
        double d3 = zz[0] * (double)e3.x + zz[1] * (double)e3.y + zz[2] * (double)e3.z + zz[3] * (double)e3.w;
        #pragma unroll
        for (int off = 32; off; off >>= 1) {
            d1 += __shfl_down(d1, off, 64);
            d2 += __shfl_down(d2, off, 64);
            d3 += __shfl_down(d3, off, 64);
        }
        if (lane == 0) {
            double s1 = enorm64[x1] - 2.0 * d1;
            double s2 = enorm64[x2] - 2.0 * d2;
            double s3 = enorm64[x3] - 2.0 * d3;
            int wbest = x1; double sw = s1;
            if (s2 < sw || (s2 == sw && x2 < wbest)) { sw = s2; wbest = x2; }
            if (s3 < sw || (s3 == sw && x3 < wbest)) { sw = s3; wbest = x3; }
            if (wbest != x1) {
                idx32[t] = wbest;
                out_idx[t] = (float)wbest;
                atomicSub(&cnt[x1], 1);
                atomicAdd(&cnt[wbest], 1);
            }
        }
    }
}

// ---------------- fp64 full-row recheck of band-flagged tokens ----------------
__global__ void k_recheck(const float* __restrict__ z, const float* __restrict__ emb,
                          const double* __restrict__ enorm64,
                          const int* __restrict__ flagList, const int* __restrict__ flagCount,
                          int* __restrict__ idx32, int* __restrict__ cnt,
                          float* __restrict__ out_idx) {
    __shared__ float zrow[E_DIM];
    __shared__ double rv[1024];
    __shared__ int ri[1024];
    const int tid = threadIdx.x;
    const int nf = *flagCount;
    for (int f = blockIdx.x; f < nf; f += gridDim.x) {
        const int t = flagList[f];
        const int b = t >> 12, x = t & 4095;
        __syncthreads();
        if (tid < E_DIM) zrow[tid] = z[(size_t)(b * 256 + tid) * 4096 + x];
        __syncthreads();
        double best = 1e300; int bi = IBIG;
        for (int s = 0; s < N_E / 1024; s++) {
            int j = s * 1024 + tid;
            const float4* er4 = (const float4*)(emb + (size_t)j * E_DIM);
            double a0 = 0.0, a1 = 0.0, a2 = 0.0, a3 = 0.0;
            for (int k4 = 0; k4 < 64; ++k4) {
                float4 e = er4[k4];
                a0 = fma((double)e.x, (double)zrow[k4 * 4 + 0], a0);
                a1 = fma((double)e.y, (double)zrow[k4 * 4 + 1], a1);
                a2 = fma((double)e.z, (double)zrow[k4 * 4 + 2], a2);
                a3 = fma((double)e.w, (double)zrow[k4 * 4 + 3], a3);
            }
            double d = enorm64[j] - 2.0 * ((a0 + a1) + (a2 + a3));
            if (d < best || (d == best && j < bi)) { best = d; bi = j; }
        }
        rv[tid] = best; ri[tid] = bi;
        __syncthreads();
        for (int off = 512; off; off >>= 1) {
            if (tid < off) {
                if (rv[tid + off] < rv[tid] ||
                    (rv[tid + off] == rv[tid] && ri[tid + off] < ri[tid])) {
                    rv[tid] = rv[tid + off]; ri[tid] = ri[tid + off];
                }
            }
            __syncthreads();
        }
        if (tid == 0) {
            int old = idx32[t];
            int nw = ri[0];
            if (nw != old) {
                idx32[t] = nw;
                out_idx[t] = (float)nw;
                atomicSub(&cnt[old], 1);
                atomicAdd(&cnt[nw], 1);
            }
        }
        __syncthreads();
    }
}

// ---------------- exclusive scan of cnt[4096] + n/usage stats ----------------
__global__ void k_scan(const int* __restrict__ cnt, int* __restrict__ offs,
                       const float* __restrict__ cluster_size,
                       float* __restrict__ nval, float* __restrict__ out_usage) {
    __shared__ int sc[1024];
    __shared__ float sn[1024];
    __shared__ float su[1024];
    int tid = threadIdx.x;
    int c0 = cnt[tid * 4], c1 = cnt[tid * 4 + 1], c2 = cnt[tid * 4 + 2], c3 = cnt[tid * 4 + 3];
    int ls = c0 + c1 + c2 + c3;
    float ns = 0.f, us = 0.f;
    {
        int cc[4] = {c0, c1, c2, c3};
        #pragma unroll
        for (int u = 0; u < 4; ++u) {
            ns += cluster_size[tid * 4 + u] * DECAY + (1.f - DECAY) * (float)cc[u];
            us += (cc[u] > 0) ? 1.f : 0.f;
        }
    }
    sc[tid] = ls; sn[tid] = ns; su[tid] = us;
    __syncthreads();
    for (int off = 1; off < 1024; off <<= 1) {
        int v = (tid >= off) ? sc[tid - off] : 0;
        __syncthreads();
        sc[tid] += v;
        __syncthreads();
    }
    int base = sc[tid] - ls;
    offs[tid * 4] = base;
    offs[tid * 4 + 1] = base + c0;
    offs[tid * 4 + 2] = base + c0 + c1;
    offs[tid * 4 + 3] = base + c0 + c1 + c2;
    for (int off = 512; off; off >>= 1) {
        if (tid < off) { sn[tid] += sn[tid + off]; su[tid] += su[tid + off]; }
        __syncthreads();
    }
    if (tid == 0) { *nval = sn[0]; *out_usage = su[0] / (float)N_E; }
}

// ---------------- place tokens into per-code lists ----------------
__global__ void k_place(const int* __restrict__ idx32, int* __restrict__ offs,
                        int* __restrict__ tokList) {
    int t = blockIdx.x * blockDim.x + threadIdx.x;
    if (t >= NTOK) return;
    int j = idx32[t];
    int p = atomicAdd(&offs[j], 1);
    tokList[p] = t;
}

// ---------------- dw: per-code coalesced reduction, 4 lane-groups ----------------
__global__ void k_dw(const unsigned short* __restrict__ zh,
                     const int* __restrict__ cnt, const int* __restrict__ offs,
                     const int* __restrict__ tokList, float* __restrict__ dw) {
    __shared__ float red[4][256];
    int j = blockIdx.x;
    int g = threadIdx.x >> 6;
    int lane = threadIdx.x & 63;
    int n = cnt[j];
    int s0 = offs[j] - n;     // offs holds end positions after k_place
    float4 acc = make_float4(0.f, 0.f, 0.f, 0.f);
    for (int i = g; i < n; i += 4) {
        int t = tokList[s0 + i];
        ushort4 h = *(const ushort4*)&zh[(size_t)t * 256 + lane * 4];
        acc.x += h2f(h.x);
        acc.y += h2f(h.y);
        acc.z += h2f(h.z);
        acc.w += h2f(h.w);
    }
    red[g][lane * 4 + 0] = acc.x; red[g][lane * 4 + 1] = acc.y;
    red[g][lane * 4 + 2] = acc.z; red[g][lane * 4 + 3] = acc.w;
    __syncthreads();
    if (g == 0) {
        #pragma unroll
        for (int u = 0; u < 4; ++u) {
            int c = lane * 4 + u;
            dw[(size_t)j * 256 + c] = red[0][c] + red[1][c] + red[2][c] + red[3][c];
        }
    }
}

// ---------------- zq gather ----------------
__global__ void k_zq(const float* __restrict__ emb, const int* __restrict__ idx32,
                     float* __restrict__ out_zq) {
    int t = blockIdx.x * blockDim.x + threadIdx.x;
    int j = idx32[t];
    int b = t >> 12, x = t & 4095;
    const float4* er = (const float4*)(emb + (size_t)j * E_DIM);
    float* ob = out_zq + (size_t)b * (E_DIM * ZX) + x;
    #pragma unroll 8
    for (int c4 = 0; c4 < E_DIM / 4; c4++) {
        float4 v = er[c4];
        ob[(size_t)(c4 * 4 + 0) * ZX] = v.x;
        ob[(size_t)(c4 * 4 + 1) * ZX] = v.y;
        ob[(size_t)(c4 * 4 + 2) * ZX] = v.z;
        ob[(size_t)(c4 * 4 + 3) * ZX] = v.w;
    }
}

// ---------------- EMA epilogue ----------------
__global__ void k_final(const float* __restrict__ cluster_size, const int* __restrict__ cnt,
                        const float* __restrict__ emb_avg, const float* __restrict__ dw,
                        const float* __restrict__ nval,
                        float* __restrict__ out_cluster, float* __restrict__ out_avg,
                        float* __restrict__ out_embed) {
    int j = blockIdx.x;
    int k = threadIdx.x;
    float nc = cluster_size[j] * DECAY + (1.f - DECAY) * (float)cnt[j];
    float n = *nval;
    float cs = (nc + EPSV) / (n + (float)N_E * EPSV) * n;
    float na = emb_avg[(size_t)j * E_DIM + k] * DECAY + (1.f - DECAY) * dw[(size_t)j * E_DIM + k];
    out_avg[(size_t)j * E_DIM + k] = na;
    out_embed[(size_t)j * E_DIM + k] = na / cs;
    if (k == 0) out_cluster[j] = nc;
}

extern "C" void kernel_launch(void* const* d_in, const int* in_sizes, int n_in,
                              void* d_out, int out_size, void* d_ws, size_t ws_size,
                              hipStream_t stream) {
    const float* z            = (const float*)d_in[0];
    const float* emb          = (const float*)d_in[1];
    const float* cluster_size = (const float*)d_in[2];
    const float* emb_avg      = (const float*)d_in[3];
    float* out = (float*)d_out;

    // ---- d_ws layout (bytes), ~17.4 MB ----
    char* ws = (char*)d_ws;
    unsigned short* zh   = (unsigned short*)(ws + 0);          // 16,777,216 (f16)
    float* enorm32       = (float*)(ws + 16777216);            // 16,384
    double* enorm64      = (double*)(ws + 16793600);           // 32,768
    int* idx32           = (int*)(ws + 16826368);              // 131,072
    int* flagList        = (int*)(ws + 16957440);              // 131,072
    int* flagList2       = (int*)(ws + 17088512);              // 131,072
    int* xpair           = (int*)(ws + 17219584);              // 131,072
    int* cnt             = (int*)(ws + 17350656);              // 16,384
    int* offs            = (int*)(ws + 17367040);              // 16,384
    int* flagCnt         = (int*)(ws + 17383424);              // 64
    int* flagCnt2        = (int*)(ws + 17383488);              // 64
    float* nval          = (float*)(ws + 17383552);            // 64

    // ---- scratch inside d_out's zq region (zq written last) ----
    float* pm1           = out + 0;                 // 1,048,576 f each
    float* pm2           = out + 1048576;
    float* pm3           = out + 2097152;
    float* pm4           = out + 3145728;
    int*   pxA           = (int*)(out + 4194304);
    int*   pxB           = (int*)(out + 5242880);
    float* dw            = out + 6291456;           // 1,048,576 f
    unsigned short* Bp   = (unsigned short*)(out + 7340032);   // 2,097,152 B
    int*   tokList       = (int*)(out + 7864320);   // 32,768 i (ends 7,897,088 < 8,388,608)

    // ---- output sections ----
    float* out_zq      = out + 0;
    float* out_idx     = out + 8388608;
    float* out_cluster = out + 8421376;
    float* out_avg     = out + 8425472;
    float* out_embed   = out + 9474048;
    float* out_usage   = out + 10522624;

    hipLaunchKernelGGL(k_prep_z, dim3(2048), dim3(256), 0, stream, z, zh);
    hipLaunchKernelGGL(k_prep_e, dim3(1024), dim3(256), 0, stream, emb, Bp, enorm32, enorm64,
                       cnt, flagCnt, flagCnt2);
    hipLaunchKernelGGL(k_dist,   dim3(256, NJB), dim3(256), 0, stream,
                       zh, Bp, enorm32, pm1, pm2, pm3, pm4, pxA, pxB);
    hipLaunchKernelGGL(k_merge,  dim3(128), dim3(256), 0, stream,
                       pm1, pm2, pm3, pm4, pxA, pxB, idx32, cnt, out_idx,
                       xpair, flagList, flagCnt, flagList2, flagCnt2);
    hipLaunchKernelGGL(k_tri,    dim3(512), dim3(256), 0, stream,
                       z, emb, enorm64, flagList, flagCnt, xpair, idx32, cnt, out_idx);
    hipLaunchKernelGGL(k_recheck, dim3(512), dim3(1024), 0, stream,
                       z, emb, enorm64, flagList2, flagCnt2, idx32, cnt, out_idx);
    hipLaunchKernelGGL(k_scan,   dim3(1), dim3(1024), 0, stream, cnt, offs,
                       cluster_size, nval, out_usage);
    hipLaunchKernelGGL(k_place,  dim3(128), dim3(256), 0, stream, idx32, offs, tokList);
    hipLaunchKernelGGL(k_dw,     dim3(4096), dim3(256), 0, stream, zh, cnt, offs, tokList, dw);
    hipLaunchKernelGGL(k_final,  dim3(4096), dim3(256), 0, stream,
                       cluster_size, cnt, emb_avg, dw, nval,
                       out_cluster, out_avg, out_embed);
    hipLaunchKernelGGL(k_zq,     dim3(128), dim3(256), 0, stream, emb, idx32, out_zq);
}

// Round 7
// 525.347 us; speedup vs baseline: 1.6381x; 1.4895x over previous
//
#include <hip/hip_runtime.h>

#define N_E   4096
#define E_DIM 256
#define NTOK  32768
#define ZX    4096
#define DECAY 0.99f
#define EPSV  1e-5f
#define TAU   0.3f
#define NJB   32        // N_E / 128 j-blocks
#define NHALF 64        // 64-col halves
#define IBIG  0x7fffffff

typedef _Float16 half8 __attribute__((ext_vector_type(8)));
typedef __attribute__((ext_vector_type(4))) float f32x4;

__device__ __forceinline__ unsigned short f2h(float x) {
    _Float16 h = (_Float16)x;
    unsigned short u;
    __builtin_memcpy(&u, &h, 2);
    return u;
}
__device__ __forceinline__ float h2f(unsigned short u) {
    _Float16 h;
    __builtin_memcpy(&h, &u, 2);
    return (float)h;
}
__device__ __forceinline__ bool flt(float v, int i, float w, int j) {
    return v < w || (v == w && i < j);
}
__device__ __forceinline__ void gload16(const void* g, void* l) {
    __builtin_amdgcn_global_load_lds(
        (const __attribute__((address_space(1))) char*)g,
        (__attribute__((address_space(3))) char*)l, 16, 0, 0);
}

// ---------------- prep z: (b,c,x) fp32 -> zh [t][c] f16 ----------------
__global__ void k_prep_z(const float* __restrict__ z, unsigned short* __restrict__ zh) {
    __shared__ float lt[64][65];
    const int bid = blockIdx.x;
    const int xt = bid & 63, ct = (bid >> 6) & 3, b = bid >> 8;
    const int tid = threadIdx.x;
    #pragma unroll
    for (int r = 0; r < 4; ++r) {
        int cy = r * 16 + (tid >> 4);
        int xx4 = tid & 15;
        float4 v = ((const float4*)z)[(size_t)(b * 256 + ct * 64 + cy) * 1024 + xt * 16 + xx4];
        lt[cy][xx4 * 4 + 0] = v.x; lt[cy][xx4 * 4 + 1] = v.y;
        lt[cy][xx4 * 4 + 2] = v.z; lt[cy][xx4 * 4 + 3] = v.w;
    }
    __syncthreads();
    #pragma unroll
    for (int it = 0; it < 2; ++it) {
        int tl = it * 32 + (tid >> 3);
        int c8 = tid & 7;
        unsigned short h[8];
        #pragma unroll
        for (int u = 0; u < 8; ++u) h[u] = f2h(lt[c8 * 8 + u][tl]);
        size_t t = (size_t)(b * 4096 + xt * 64 + tl);
        size_t o = t * 256 + ct * 64 + c8 * 8;
        *(ushort4*)&zh[o]     = make_ushort4(h[0], h[1], h[2], h[3]);
        *(ushort4*)&zh[o + 4] = make_ushort4(h[4], h[5], h[6], h[7]);
    }
}

// ---------------- prep emb: Bp = e (f16), enorm32/64; fused init ----------------
__global__ void k_prep_e(const float* __restrict__ emb, unsigned short* __restrict__ Bp,
                         float* __restrict__ enorm32, double* __restrict__ enorm64,
                         int* __restrict__ cnt, int* __restrict__ flagCnt,
                         int* __restrict__ flagCnt2) {
    if (threadIdx.x < 4) cnt[blockIdx.x * 4 + threadIdx.x] = 0;
    if (blockIdx.x == 0 && threadIdx.x == 0) { *flagCnt = 0; *flagCnt2 = 0; }
    int j = blockIdx.x * 4 + (threadIdx.x >> 6);
    int lane = threadIdx.x & 63;
    float4 v = ((const float4*)emb)[(size_t)j * 64 + lane];
    float f[4] = {v.x, v.y, v.z, v.w};
    unsigned short h[4];
    #pragma unroll
    for (int u = 0; u < 4; ++u) h[u] = f2h(f[u]);
    *(ushort4*)&Bp[(size_t)j * E_DIM + lane * 4] = make_ushort4(h[0], h[1], h[2], h[3]);
    double s = 0.0;
    #pragma unroll
    for (int u = 0; u < 4; ++u) s += (double)f[u] * (double)f[u];
    #pragma unroll
    for (int off = 32; off; off >>= 1) s += __shfl_down(s, off, 64);
    if (lane == 0) { enorm32[j] = (float)s; enorm64[j] = s; }
}

// ---------------- MFMA f16 distance; per-half top-2 + band count ----------------
__global__ __launch_bounds__(256) void k_dist(
        const unsigned short* __restrict__ zh,
        const unsigned short* __restrict__ Bp, const float* __restrict__ enorm32,
        float* __restrict__ pm1h, float* __restrict__ pm2h, int* __restrict__ pxh,
        unsigned char* __restrict__ pcnt) {
    __shared__ __align__(16) char smem[65536];   // 2 x (16KB A + 16KB B)
    const int tid = threadIdx.x;
    const int lane = tid & 63;
    const int w = tid >> 6;
    const int wr = w >> 1, wc = w & 1;
    const int t0 = blockIdx.x * 128;
    const int jb = blockIdx.y;
    const int j0 = jb * 128;
    const int sw16 = (((lane & 7) ^ (lane >> 3)) << 4);
    const int rowsub = lane >> 3;

    f32x4 acc[4][4];
    #pragma unroll
    for (int m = 0; m < 4; ++m)
        #pragma unroll
        for (int nn = 0; nn < 4; ++nn)
            acc[m][nn] = (f32x4){0.f, 0.f, 0.f, 0.f};

    auto stage = [&](int s, int buf) {
        const int kb = s * 128 + sw16;
        char* base = smem + buf * 32768;
        #pragma unroll
        for (int c = 0; c < 4; ++c) {
            int seg = w * 4 + c;
            int arow = t0 + seg * 8 + rowsub;
            int brow = j0 + seg * 8 + rowsub;
            gload16((const char*)zh + (size_t)arow * 512 + kb, base + seg * 1024);
            gload16((const char*)Bp + (size_t)brow * 512 + kb, base + 16384 + seg * 1024);
        }
    };

    stage(0, 0);
    __syncthreads();
    for (int s = 0; s < 4; ++s) {
        const int buf = s & 1;
        if (s < 3) stage(s + 1, buf ^ 1);
        const int xr = ((lane & 7) << 4);
        #pragma unroll
        for (int kk = 0; kk < 2; ++kk) {
            const int colb = (kk * 64 + ((lane >> 4) << 4)) ^ xr;
            half8 a[4], b[4];
            #pragma unroll
            for (int m = 0; m < 4; ++m)
                a[m] = *(const half8*)&smem[buf * 32768
                        + ((wr * 64 + m * 16 + (lane & 15)) << 7) + colb];
            #pragma unroll
            for (int nn = 0; nn < 4; ++nn)
                b[nn] = *(const half8*)&smem[buf * 32768 + 16384
                        + ((wc * 64 + nn * 16 + (lane & 15)) << 7) + colb];
            #pragma unroll
            for (int m = 0; m < 4; ++m)
                #pragma unroll
                for (int nn = 0; nn < 4; ++nn)
                    acc[m][nn] = __builtin_amdgcn_mfma_f32_16x16x32_f16(a[m], b[nn], acc[m][nn], 0, 0, 0);
        }
        __syncthreads();
    }

    // ---- epilogue: per-(wc)half top-2 + band-count, register butterfly only ----
    const int c0 = lane & 15;
    const int g  = lane >> 4;
    const int h  = jb * 2 + wc;
    float en[4];
    #pragma unroll
    for (int nn = 0; nn < 4; ++nn) en[nn] = enorm32[j0 + wc * 64 + nn * 16 + c0];

    #pragma unroll
    for (int m = 0; m < 4; ++m) {
        float m1[4], m2[4]; int x1[4], x2[4];
        #pragma unroll
        for (int r = 0; r < 4; ++r) { m1[r] = 3.4e38f; m2[r] = 3.4e38f; x1[r] = IBIG; x2[r] = IBIG; }
        #pragma unroll
        for (int nn = 0; nn < 4; ++nn) {
            int j = j0 + wc * 64 + nn * 16 + c0;
            #pragma unroll
            for (int r = 0; r < 4; ++r) {
                float sc = fmaf(-2.f, acc[m][nn][r], en[nn]);
                if (flt(sc, j, m1[r], x1[r])) { m2[r] = m1[r]; x2[r] = x1[r]; m1[r] = sc; x1[r] = j; }
                else if (flt(sc, j, m2[r], x2[r])) { m2[r] = sc; x2[r] = j; }
            }
        }
        #pragma unroll
        for (int off = 8; off >= 1; off >>= 1) {
            #pragma unroll
            for (int r = 0; r < 4; ++r) {
                float om1 = __shfl_xor(m1[r], off, 64);
                int   ox1 = __shfl_xor(x1[r], off, 64);
                float om2 = __shfl_xor(m2[r], off, 64);
                int   ox2 = __shfl_xor(x2[r], off, 64);
                bool take = flt(om1, ox1, m1[r], x1[r]);
                float l1 = take ? om1 : m1[r];  int i1 = take ? ox1 : x1[r];
                float cv = take ? m1[r] : om1;  int ci = take ? x1[r] : ox1;   // loser top1
                float dv = take ? om2 : m2[r];  int di = take ? ox2 : x2[r];   // winner's m2
                bool t2 = flt(dv, di, cv, ci);
                m1[r] = l1; x1[r] = i1;
                m2[r] = t2 ? dv : cv; x2[r] = t2 ? di : ci;
            }
        }
        // band counts vs merged half-min
        int bc[4] = {0, 0, 0, 0};
        #pragma unroll
        for (int nn = 0; nn < 4; ++nn)
            #pragma unroll
            for (int r = 0; r < 4; ++r) {
                float sc = fmaf(-2.f, acc[m][nn][r], en[nn]);
                bc[r] += (sc < m1[r] + TAU) ? 1 : 0;
            }
        #pragma unroll
        for (int off = 8; off >= 1; off >>= 1)
            #pragma unroll
            for (int r = 0; r < 4; ++r)
                bc[r] += __shfl_xor(bc[r], off, 64);
        if ((lane & 15) == 0) {
            #pragma unroll
            for (int r = 0; r < 4; ++r) {
                int t = t0 + wr * 64 + m * 16 + g * 4 + r;
                size_t o = (size_t)h * NTOK + t;
                pm1h[o] = m1[r];
                pm2h[o] = m2[r];
                pxh[o] = (x1[r] & 0xffff) | (x2[r] << 16);
                pcnt[o] = (unsigned char)(bc[r] > 255 ? 255 : bc[r]);
            }
        }
    }
}

// ---------------- merge halves, histogram, candidate collection ----------------
__global__ void k_merge(const float* __restrict__ pm1h, const float* __restrict__ pm2h,
                        const int* __restrict__ pxh, const unsigned char* __restrict__ pcnt,
                        int* __restrict__ idx32, int* __restrict__ cnt,
                        float* __restrict__ out_idx,
                        int* __restrict__ xlist, int* __restrict__ xn,
                        int* __restrict__ flagList, int* __restrict__ flagCount,
                        int* __restrict__ flagList2, int* __restrict__ flagCount2) {
    int t = blockIdx.x * blockDim.x + threadIdx.x;
    if (t >= NTOK) return;
    float m1 = 3.4e38f, m2 = 3.4e38f; int x1 = IBIG, x2 = IBIG;
    for (int s = 0; s < NHALF; s++) {
        size_t o = (size_t)s * NTOK + t;
        float a = pm1h[o], b = pm2h[o];
        int p = pxh[o];
        int ia = p & 0xffff, ib = (p >> 16) & 0xffff;
        if (flt(a, ia, m1, x1)) { m2 = m1; x2 = x1; m1 = a; x1 = ia; }
        else if (flt(a, ia, m2, x2)) { m2 = a; x2 = ia; }
        if (flt(b, ib, m1, x1)) { m2 = m1; x2 = x1; m1 = b; x1 = ib; }
        else if (flt(b, ib, m2, x2)) { m2 = b; x2 = ib; }
    }
    idx32[t] = x1;
    atomicAdd(&cnt[x1], 1);
    out_idx[t] = (float)x1;
    if (m2 - m1 >= TAU) return;          // winner certain at fp16 precision
    const float thr = m1 + TAU;
    int nc = 0; bool full = false;
    for (int s = 0; s < NHALF; s++) {
        size_t o = (size_t)s * NTOK + t;
        float a = pm1h[o];
        if (a >= thr) continue;
        if (pcnt[o] > 2) { full = true; break; }
        int p = pxh[o];
        if (nc == 8) { full = true; break; }
        xlist[t * 8 + nc] = p & 0xffff; nc++;
        float b = pm2h[o];
        if (b < thr) {
            if (nc == 8) { full = true; break; }
            xlist[t * 8 + nc] = (p >> 16) & 0xffff; nc++;
        }
    }
    if (full) {
        int q = atomicAdd(flagCount2, 1);
        flagList2[q] = t;
    } else {
        xn[t] = nc;
        int q = atomicAdd(flagCount, 1);
        flagList[q] = t;
    }
}

// ---------------- exact fp64 referee over candidate list ----------------
__global__ void k_tri(const float* __restrict__ z, const float* __restrict__ emb,
                      const double* __restrict__ enorm64,
                      const int* __restrict__ flagList, const int* __restrict__ flagCount,
                      const int* __restrict__ xlist, const int* __restrict__ xn,
                      int* __restrict__ idx32, int* __restrict__ cnt,
                      float* __restrict__ out_idx) {
    const int lane = threadIdx.x & 63;
    const int wid = blockIdx.x * (blockDim.x >> 6) + (threadIdx.x >> 6);
    const int nw = gridDim.x * (blockDim.x >> 6);
    const int nf = *flagCount;
    for (int f = wid; f < nf; f += nw) {
        int t = flagList[f];
        int b = t >> 12, x = t & 4095;
        double zz[4];
        #pragma unroll
        for (int u = 0; u < 4; ++u)
            zz[u] = (double)z[(size_t)(b * 256 + lane * 4 + u) * 4096 + x];
        int m = xn[t];
        double best = 1e300; int bi = IBIG;
        for (int c = 0; c < m; ++c) {
            int j = xlist[t * 8 + c];
            float4 e = ((const float4*)emb)[(size_t)j * 64 + lane];
            double d = zz[0] * (double)e.x + zz[1] * (double)e.y
                     + zz[2] * (double)e.z + zz[3] * (double)e.w;
            #pragma unroll
            for (int off = 32; off; off >>= 1) d += __shfl_down(d, off, 64);
            double s = enorm64[j] - 2.0 * d;   // valid on lane 0
            if (s < best || (s == best && j < bi)) { best = s; bi = j; }
        }
        if (lane == 0) {
            int old = idx32[t];
            if (bi != old) {
                idx32[t] = bi;
                out_idx[t] = (float)bi;
                atomicSub(&cnt[old], 1);
                atomicAdd(&cnt[bi], 1);
            }
        }
    }
}

// ---------------- fp64 full-row recheck (rare fallback) ----------------
__global__ void k_recheck(const float* __restrict__ z, const float* __restrict__ emb,
                          const double* __restrict__ enorm64,
                          const int* __restrict__ flagList, const int* __restrict__ flagCount,
                          int* __restrict__ idx32, int* __restrict__ cnt,
                          float* __restrict__ out_idx) {
    __shared__ float zrow[E_DIM];
    __shared__ double rv[1024];
    __shared__ int ri[1024];
    const int tid = threadIdx.x;
    const int nf = *flagCount;
    for (int f = blockIdx.x; f < nf; f += gridDim.x) {
        const int t = flagList[f];
        const int b = t >> 12, x = t & 4095;
        __syncthreads();
        if (tid < E_DIM) zrow[tid] = z[(size_t)(b * 256 + tid) * 4096 + x];
        __syncthreads();
        double best = 1e300; int bi = IBIG;
        for (int s = 0; s < N_E / 1024; s++) {
            int j = s * 1024 + tid;
            const float4* er4 = (const float4*)(emb + (size_t)j * E_DIM);
            double a0 = 0.0, a1 = 0.0, a2 = 0.0, a3 = 0.0;
            for (int k4 = 0; k4 < 64; ++k4) {
                float4 e = er4[k4];
                a0 = fma((double)e.x, (double)zrow[k4 * 4 + 0], a0);
                a1 = fma((double)e.y, (double)zrow[k4 * 4 + 1], a1);
                a2 = fma((double)e.z, (double)zrow[k4 * 4 + 2], a2);
                a3 = fma((double)e.w, (double)zrow[k4 * 4 + 3], a3);
            }
            double d = enorm64[j] - 2.0 * ((a0 + a1) + (a2 + a3));
            if (d < best || (d == best && j < bi)) { best = d; bi = j; }
        }
        rv[tid] = best; ri[tid] = bi;
        __syncthreads();
        for (int off = 512; off; off >>= 1) {
            if (tid < off) {
                if (rv[tid + off] < rv[tid] ||
                    (rv[tid + off] == rv[tid] && ri[tid + off] < ri[tid])) {
                    rv[tid] = rv[tid + off]; ri[tid] = ri[tid + off];
                }
            }
            __syncthreads();
        }
        if (tid == 0) {
            int old = idx32[t];
            int nw = ri[0];
            if (nw != old) {
                idx32[t] = nw;
                out_idx[t] = (float)nw;
                atomicSub(&cnt[old], 1);
                atomicAdd(&cnt[nw], 1);
            }
        }
        __syncthreads();
    }
}

// ---------------- exclusive scan of cnt[4096] + n/usage stats ----------------
__global__ void k_scan(const int* __restrict__ cnt, int* __restrict__ offs,
                       const float* __restrict__ cluster_size,
                       float* __restrict__ nval, float* __restrict__ out_usage) {
    __shared__ int sc[1024];
    __shared__ float sn[1024];
    __shared__ float su[1024];
    int tid = threadIdx.x;
    int c0 = cnt[tid * 4], c1 = cnt[tid * 4 + 1], c2 = cnt[tid * 4 + 2], c3 = cnt[tid * 4 + 3];
    int ls = c0 + c1 + c2 + c3;
    float ns = 0.f, us = 0.f;
    {
        int cc[4] = {c0, c1, c2, c3};
        #pragma unroll
        for (int u = 0; u < 4; ++u) {
            ns += cluster_size[tid * 4 + u] * DECAY + (1.f - DECAY) * (float)cc[u];
            us += (cc[u] > 0) ? 1.f : 0.f;
        }
    }
    sc[tid] = ls; sn[tid] = ns; su[tid] = us;
    __syncthreads();
    for (int off = 1; off < 1024; off <<= 1) {
        int v = (tid >= off) ? sc[tid - off] : 0;
        __syncthreads();
        sc[tid] += v;
        __syncthreads();
    }
    int base = sc[tid] - ls;
    offs[tid * 4] = base;
    offs[tid * 4 + 1] = base + c0;
    offs[tid * 4 + 2] = base + c0 + c1;
    offs[tid * 4 + 3] = base + c0 + c1 + c2;
    for (int off = 512; off; off >>= 1) {
        if (tid < off) { sn[tid] += sn[tid + off]; su[tid] += su[tid + off]; }
        __syncthreads();
    }
    if (tid == 0) { *nval = sn[0]; *out_usage = su[0] / (float)N_E; }
}

// ---------------- place tokens into per-code lists ----------------
__global__ void k_place(const int* __restrict__ idx32, int* __restrict__ offs,
                        int* __restrict__ tokList) {
    int t = blockIdx.x * blockDim.x + threadIdx.x;
    if (t >= NTOK) return;
    int j = idx32[t];
    int p = atomicAdd(&offs[j], 1);
    tokList[p] = t;
}

// ---------------- dw: per-code coalesced reduction, 4 lane-groups ----------------
__global__ void k_dw(const unsigned short* __restrict__ zh,
                     const int* __restrict__ cnt, const int* __restrict__ offs,
                     const int* __restrict__ tokList, float* __restrict__ dw) {
    __shared__ float red[4][256];
    int j = blockIdx.x;
    int g = threadIdx.x >> 6;
    int lane = threadIdx.x & 63;
    int n = cnt[j];
    int s0 = offs[j] - n;     // offs holds end positions after k_place
    float4 acc = make_float4(0.f, 0.f, 0.f, 0.f);
    for (int i = g; i < n; i += 4) {
        int t = tokList[s0 + i];
        ushort4 h = *(const ushort4*)&zh[(size_t)t * 256 + lane * 4];
        acc.x += h2f(h.x);
        acc.y += h2f(h.y);
        acc.z += h2f(h.z);
        acc.w += h2f(h.w);
    }
    red[g][lane * 4 + 0] = acc.x; red[g][lane * 4 + 1] = acc.y;
    red[g][lane * 4 + 2] = acc.z; red[g][lane * 4 + 3] = acc.w;
    __syncthreads();
    if (g == 0) {
        #pragma unroll
        for (int u = 0; u < 4; ++u) {
            int c = lane * 4 + u;
            dw[(size_t)j * 256 + c] = red[0][c] + red[1][c] + red[2][c] + red[3][c];
        }
    }
}

// ---------------- zq gather ----------------
__global__ void k_zq(const float* __restrict__ emb, const int* __restrict__ idx32,
                     float* __restrict__ out_zq) {
    int t = blockIdx.x * blockDim.x + threadIdx.x;
    int j = idx32[t];
    int b = t >> 12, x = t & 4095;
    const float4* er = (const float4*)(emb + (size_t)j * E_DIM);
    float* ob = out_zq + (size_t)b * (E_DIM * ZX) + x;
    #pragma unroll 8
    for (int c4 = 0; c4 < E_DIM / 4; c4++) {
        float4 v = er[c4];
        ob[(size_t)(c4 * 4 + 0) * ZX] = v.x;
        ob[(size_t)(c4 * 4 + 1) * ZX] = v.y;
        ob[(size_t)(c4 * 4 + 2) * ZX] = v.z;
        ob[(size_t)(c4 * 4 + 3) * ZX] = v.w;
    }
}

// ---------------- EMA epilogue ----------------
__global__ void k_final(const float* __restrict__ cluster_size, const int* __restrict__ cnt,
                        const float* __restrict__ emb_avg, const float* __restrict__ dw,
                        const float* __restrict__ nval,
                        float* __restrict__ out_cluster, float* __restrict__ out_avg,
                        float* __restrict__ out_embed) {
    int j = blockIdx.x;
    int k = threadIdx.x;
    float nc = cluster_size[j] * DECAY + (1.f - DECAY) * (float)cnt[j];
    float n = *nval;
    float cs = (nc + EPSV) / (n + (float)N_E * EPSV) * n;
    float na = emb_avg[(size_t)j * E_DIM + k] * DECAY + (1.f - DECAY) * dw[(size_t)j * E_DIM + k];
    out_avg[(size_t)j * E_DIM + k] = na;
    out_embed[(size_t)j * E_DIM + k] = na / cs;
    if (k == 0) out_cluster[j] = nc;
}

extern "C" void kernel_launch(void* const* d_in, const int* in_sizes, int n_in,
                              void* d_out, int out_size, void* d_ws, size_t ws_size,
                              hipStream_t stream) {
    const float* z            = (const float*)d_in[0];
    const float* emb          = (const float*)d_in[1];
    const float* cluster_size = (const float*)d_in[2];
    const float* emb_avg      = (const float*)d_in[3];
    float* out = (float*)d_out;

    // ---- d_ws layout (bytes), ~20.5 MB ----
    char* ws = (char*)d_ws;
    unsigned short* zh   = (unsigned short*)(ws + 0);          // 16,777,216 (f16)
    unsigned char* pcnt  = (unsigned char*)(ws + 16777216);    // 2,097,152
    float* enorm32       = (float*)(ws + 18874368);            // 16,384
    double* enorm64      = (double*)(ws + 18890752);           // 32,768
    int* idx32           = (int*)(ws + 18923520);              // 131,072
    int* flagList        = (int*)(ws + 19054592);              // 131,072
    int* flagList2       = (int*)(ws + 19185664);              // 131,072
    int* xlist           = (int*)(ws + 19316736);              // 1,048,576
    int* xn              = (int*)(ws + 20365312);              // 131,072
    int* cnt             = (int*)(ws + 20496384);              // 16,384
    int* offs            = (int*)(ws + 20512768);              // 16,384
    int* flagCnt         = (int*)(ws + 20529152);              // 64
    int* flagCnt2        = (int*)(ws + 20529216);              // 64
    float* nval          = (float*)(ws + 20529280);            // 64

    // ---- scratch inside d_out's zq region (zq written last) ----
    float* pm1h          = out + 0;                 // 2,097,152 f (8 MB)
    float* pm2h          = out + 2097152;           // 2,097,152 f
    int*   pxh           = (int*)(out + 4194304);   // 2,097,152 i
    float* dw            = out + 6291456;           // 1,048,576 f
    unsigned short* Bp   = (unsigned short*)(out + 7340032);   // 2,097,152 B
    int*   tokList       = (int*)(out + 7864320);   // 32,768 i (ends 7,897,088)

    // ---- output sections ----
    float* out_zq      = out + 0;
    float* out_idx     = out + 8388608;
    float* out_cluster = out + 8421376;
    float* out_avg     = out + 8425472;
    float* out_embed   = out + 9474048;
    float* out_usage   = out + 10522624;

    hipLaunchKernelGGL(k_prep_z, dim3(2048), dim3(256), 0, stream, z, zh);
    hipLaunchKernelGGL(k_prep_e, dim3(1024), dim3(256), 0, stream, emb, Bp, enorm32, enorm64,
                       cnt, flagCnt, flagCnt2);
    hipLaunchKernelGGL(k_dist,   dim3(256, NJB), dim3(256), 0, stream,
                       zh, Bp, enorm32, pm1h, pm2h, pxh, pcnt);
    hipLaunchKernelGGL(k_merge,  dim3(128), dim3(256), 0, stream,
                       pm1h, pm2h, pxh, pcnt, idx32, cnt, out_idx,
                       xlist, xn, flagList, flagCnt, flagList2, flagCnt2);
    hipLaunchKernelGGL(k_tri,    dim3(512), dim3(256), 0, stream,
                       z, emb, enorm64, flagList, flagCnt, xlist, xn, idx32, cnt, out_idx);
    hipLaunchKernelGGL(k_recheck, dim3(512), dim3(1024), 0, stream,
                       z, emb, enorm64, flagList2, flagCnt2, idx32, cnt, out_idx);
    hipLaunchKernelGGL(k_scan,   dim3(1), dim3(1024), 0, stream, cnt, offs,
                       cluster_size, nval, out_usage);
    hipLaunchKernelGGL(k_place,  dim3(128), dim3(256), 0, stream, idx32, offs, tokList);
    hipLaunchKernelGGL(k_dw,     dim3(4096), dim3(256), 0, stream, zh, cnt, offs, tokList, dw);
    hipLaunchKernelGGL(k_final,  dim3(4096), dim3(256), 0, stream,
                       cluster_size, cnt, emb_avg, dw, nval,
                       out_cluster, out_avg, out_embed);
    hipLaunchKernelGGL(k_zq,     dim3(128), dim3(256), 0, stream, emb, idx32, out_zq);
}

// Round 8
// 294.119 us; speedup vs baseline: 2.9259x; 1.7862x over previous
//
#include <hip/hip_runtime.h>

#define N_E   4096
#define E_DIM 256
#define NTOK  32768
#define ZX    4096
#define DECAY 0.99f
#define EPSV  1e-5f
#define TAU   0.3f
#define NJB   32        // N_E / 128 j-blocks
#define NHALF 64        // 64-col halves
#define IBIG  0x7fffffff

typedef _Float16 half8 __attribute__((ext_vector_type(8)));
typedef __attribute__((ext_vector_type(4))) float f32x4;

__device__ __forceinline__ unsigned short f2h(float x) {
    _Float16 h = (_Float16)x;
    unsigned short u;
    __builtin_memcpy(&u, &h, 2);
    return u;
}
__device__ __forceinline__ float h2f(unsigned short u) {
    _Float16 h;
    __builtin_memcpy(&h, &u, 2);
    return (float)h;
}
__device__ __forceinline__ unsigned umin2(unsigned a, unsigned b) { return a < b ? a : b; }
__device__ __forceinline__ unsigned umax2(unsigned a, unsigned b) { return a > b ? a : b; }
__device__ __forceinline__ void gload16(const void* g, void* l) {
    __builtin_amdgcn_global_load_lds(
        (const __attribute__((address_space(1))) char*)g,
        (__attribute__((address_space(3))) char*)l, 16, 0, 0);
}

// ---------------- prep z: (b,c,x) fp32 -> zh [t][c] f16 ----------------
__global__ void k_prep_z(const float* __restrict__ z, unsigned short* __restrict__ zh) {
    __shared__ float lt[64][65];
    const int bid = blockIdx.x;
    const int xt = bid & 63, ct = (bid >> 6) & 3, b = bid >> 8;
    const int tid = threadIdx.x;
    #pragma unroll
    for (int r = 0; r < 4; ++r) {
        int cy = r * 16 + (tid >> 4);
        int xx4 = tid & 15;
        float4 v = ((const float4*)z)[(size_t)(b * 256 + ct * 64 + cy) * 1024 + xt * 16 + xx4];
        lt[cy][xx4 * 4 + 0] = v.x; lt[cy][xx4 * 4 + 1] = v.y;
        lt[cy][xx4 * 4 + 2] = v.z; lt[cy][xx4 * 4 + 3] = v.w;
    }
    __syncthreads();
    #pragma unroll
    for (int it = 0; it < 2; ++it) {
        int tl = it * 32 + (tid >> 3);
        int c8 = tid & 7;
        unsigned short h[8];
        #pragma unroll
        for (int u = 0; u < 8; ++u) h[u] = f2h(lt[c8 * 8 + u][tl]);
        size_t t = (size_t)(b * 4096 + xt * 64 + tl);
        size_t o = t * 256 + ct * 64 + c8 * 8;
        *(ushort4*)&zh[o]     = make_ushort4(h[0], h[1], h[2], h[3]);
        *(ushort4*)&zh[o + 4] = make_ushort4(h[4], h[5], h[6], h[7]);
    }
}

// ---------------- prep emb: Bp = e (f16), enorm32/64; fused init ----------------
__global__ void k_prep_e(const float* __restrict__ emb, unsigned short* __restrict__ Bp,
                         float* __restrict__ enorm32, double* __restrict__ enorm64,
                         int* __restrict__ cnt, int* __restrict__ flagCnt,
                         int* __restrict__ flagCnt2) {
    if (threadIdx.x < 4) cnt[blockIdx.x * 4 + threadIdx.x] = 0;
    if (blockIdx.x == 0 && threadIdx.x == 0) { *flagCnt = 0; *flagCnt2 = 0; }
    int j = blockIdx.x * 4 + (threadIdx.x >> 6);
    int lane = threadIdx.x & 63;
    float4 v = ((const float4*)emb)[(size_t)j * 64 + lane];
    float f[4] = {v.x, v.y, v.z, v.w};
    unsigned short h[4];
    #pragma unroll
    for (int u = 0; u < 4; ++u) h[u] = f2h(f[u]);
    *(ushort4*)&Bp[(size_t)j * E_DIM + lane * 4] = make_ushort4(h[0], h[1], h[2], h[3]);
    double s = 0.0;
    #pragma unroll
    for (int u = 0; u < 4; ++u) s += (double)f[u] * (double)f[u];
    #pragma unroll
    for (int off = 32; off; off >>= 1) s += __shfl_down(s, off, 64);
    if (lane == 0) { enorm32[j] = (float)s; enorm64[j] = s; }
}

// ---------------- MFMA f16 distance; per-half top-3 packed keys ----------------
__global__ __launch_bounds__(256) void k_dist(
        const unsigned short* __restrict__ zh,
        const unsigned short* __restrict__ Bp, const float* __restrict__ enorm32,
        unsigned* __restrict__ pk1, unsigned* __restrict__ pk2, unsigned* __restrict__ pk3) {
    __shared__ __align__(16) char smem[65536];   // 2 x (16KB A + 16KB B)
    const int tid = threadIdx.x;
    const int lane = tid & 63;
    const int w = tid >> 6;
    const int wr = w >> 1, wc = w & 1;
    const int t0 = blockIdx.x * 128;
    const int jb = blockIdx.y;
    const int j0 = jb * 128;
    const int sw16 = (((lane & 7) ^ (lane >> 3)) << 4);
    const int rowsub = lane >> 3;

    f32x4 acc[4][4];
    #pragma unroll
    for (int m = 0; m < 4; ++m)
        #pragma unroll
        for (int nn = 0; nn < 4; ++nn)
            acc[m][nn] = (f32x4){0.f, 0.f, 0.f, 0.f};

    auto stage = [&](int s, int buf) {
        const int kb = s * 128 + sw16;
        char* base = smem + buf * 32768;
        #pragma unroll
        for (int c = 0; c < 4; ++c) {
            int seg = w * 4 + c;
            int arow = t0 + seg * 8 + rowsub;
            int brow = j0 + seg * 8 + rowsub;
            gload16((const char*)zh + (size_t)arow * 512 + kb, base + seg * 1024);
            gload16((const char*)Bp + (size_t)brow * 512 + kb, base + 16384 + seg * 1024);
        }
    };

    stage(0, 0);
    __syncthreads();
    for (int s = 0; s < 4; ++s) {
        const int buf = s & 1;
        if (s < 3) stage(s + 1, buf ^ 1);
        const int xr = ((lane & 7) << 4);
        #pragma unroll
        for (int kk = 0; kk < 2; ++kk) {
            const int colb = (kk * 64 + ((lane >> 4) << 4)) ^ xr;
            half8 a[4], b[4];
            #pragma unroll
            for (int m = 0; m < 4; ++m)
                a[m] = *(const half8*)&smem[buf * 32768
                        + ((wr * 64 + m * 16 + (lane & 15)) << 7) + colb];
            #pragma unroll
            for (int nn = 0; nn < 4; ++nn)
                b[nn] = *(const half8*)&smem[buf * 32768 + 16384
                        + ((wc * 64 + nn * 16 + (lane & 15)) << 7) + colb];
            // swapped operands: D[row=code, col=token]
            #pragma unroll
            for (int m = 0; m < 4; ++m)
                #pragma unroll
                for (int nn = 0; nn < 4; ++nn)
                    acc[m][nn] = __builtin_amdgcn_mfma_f32_16x16x32_f16(b[nn], a[m], acc[m][nn], 0, 0, 0);
        }
        __syncthreads();
    }

    // ---- epilogue: per-half top-3 packed u32 keys; 2-pass butterfly ----
    const int g   = lane >> 4;       // code row-group
    const int gg4 = g * 4;
    const int h   = jb * 2 + wc;
    float enb[4][4];
    #pragma unroll
    for (int nn = 0; nn < 4; ++nn) {
        float4 e4 = *(const float4*)&enorm32[j0 + wc * 64 + nn * 16 + gg4];
        enb[nn][0] = e4.x + 4096.f; enb[nn][1] = e4.y + 4096.f;
        enb[nn][2] = e4.z + 4096.f; enb[nn][3] = e4.w + 4096.f;
    }
    unsigned s1 = 0, s2 = 0, s3 = 0;
    #pragma unroll
    for (int m = 0; m < 4; ++m) {
        unsigned k1 = 0xFFFFFFFFu, k2 = 0xFFFFFFFFu, k3 = 0xFFFFFFFFu;
        #pragma unroll
        for (int nn = 0; nn < 4; ++nn)
            #pragma unroll
            for (int r = 0; r < 4; ++r) {
                float sc = fmaf(-2.f, acc[m][nn][r], enb[nn][r]);   // > 0 by construction
                unsigned key = (__float_as_uint(sc) & 0xFFFFFFC0u)
                             | (unsigned)(gg4 + nn * 16 + r);
                k3 = umin2(k3, umax2(k2, key));
                k2 = umin2(k2, umax2(k1, key));
                k1 = umin2(k1, key);
            }
        #pragma unroll
        for (int off = 16; off <= 32; off <<= 1) {
            unsigned b1 = (unsigned)__shfl_xor((int)k1, off, 64);
            unsigned b2 = (unsigned)__shfl_xor((int)k2, off, 64);
            unsigned b3 = (unsigned)__shfl_xor((int)k3, off, 64);
            unsigned p  = umax2(k1, b1);
            unsigned q  = umin2(k2, b2);
            unsigned r2 = umax2(k2, b2);
            unsigned ss = umin2(k3, b3);
            k1 = umin2(k1, b1);
            k2 = umin2(p, q);
            k3 = umin2(umax2(p, q), umin2(r2, ss));
        }
        s1 = (g == m) ? k1 : s1;
        s2 = (g == m) ? k2 : s2;
        s3 = (g == m) ? k3 : s3;
    }
    size_t o = (size_t)h * NTOK + t0 + wr * 64 + lane;
    pk1[o] = s1; pk2[o] = s2; pk3[o] = s3;
}

// ---------------- merge halves on keys, histogram, candidate collection ----------------
__global__ void k_merge(const unsigned* __restrict__ pk1, const unsigned* __restrict__ pk2,
                        const unsigned* __restrict__ pk3,
                        int* __restrict__ idx32, int* __restrict__ cnt,
                        float* __restrict__ out_idx,
                        int* __restrict__ xlist, int* __restrict__ xn,
                        int* __restrict__ flagList, int* __restrict__ flagCount,
                        int* __restrict__ flagList2, int* __restrict__ flagCount2) {
    int t = blockIdx.x * blockDim.x + threadIdx.x;
    if (t >= NTOK) return;
    unsigned g1 = 0xFFFFFFFFu, g2 = 0xFFFFFFFFu;
    int h1 = 0;
    for (int s = 0; s < NHALF; s++) {
        unsigned a = pk1[(size_t)s * NTOK + t];
        unsigned b = pk2[(size_t)s * NTOK + t];
        bool c = a < g1;
        g2 = c ? g1 : umin2(g2, a);
        h1 = c ? s : h1;
        g1 = c ? a : g1;
        g2 = umin2(g2, b);          // b >= a so never the global min
    }
    int x1 = h1 * 64 + (int)(g1 & 63u);
    idx32[t] = x1;
    atomicAdd(&cnt[x1], 1);
    out_idx[t] = (float)x1;
    float v1 = __uint_as_float(g1 & 0xFFFFFFC0u);
    float v2 = __uint_as_float(g2 & 0xFFFFFFC0u);
    if (v2 - v1 >= TAU) return;     // winner certain at fp16 precision
    unsigned thrk = __float_as_uint(v1 + TAU) | 63u;
    int nc = 0; bool full = false;
    for (int s = 0; s < NHALF; s++) {
        unsigned a = pk1[(size_t)s * NTOK + t];
        if (a > thrk) continue;
        if (pk3[(size_t)s * NTOK + t] <= thrk) { full = true; break; }  // >=3 in band
        if (nc == 8) { full = true; break; }
        xlist[t * 8 + nc++] = s * 64 + (int)(a & 63u);
        unsigned b = pk2[(size_t)s * NTOK + t];
        if (b <= thrk) {
            if (nc == 8) { full = true; break; }
            xlist[t * 8 + nc++] = s * 64 + (int)(b & 63u);
        }
    }
    if (full) {
        int q = atomicAdd(flagCount2, 1);
        flagList2[q] = t;
    } else {
        xn[t] = nc;
        int q = atomicAdd(flagCount, 1);
        flagList[q] = t;
    }
}

// ---------------- exact fp64 referee over candidate list ----------------
__global__ void k_tri(const float* __restrict__ z, const float* __restrict__ emb,
                      const double* __restrict__ enorm64,
                      const int* __restrict__ flagList, const int* __restrict__ flagCount,
                      const int* __restrict__ xlist, const int* __restrict__ xn,
                      int* __restrict__ idx32, int* __restrict__ cnt,
                      float* __restrict__ out_idx) {
    const int lane = threadIdx.x & 63;
    const int wid = blockIdx.x * (blockDim.x >> 6) + (threadIdx.x >> 6);
    const int nw = gridDim.x * (blockDim.x >> 6);
    const int nf = *flagCount;
    for (int f = wid; f < nf; f += nw) {
        int t = flagList[f];
        int b = t >> 12, x = t & 4095;
        double zz[4];
        #pragma unroll
        for (int u = 0; u < 4; ++u)
            zz[u] = (double)z[(size_t)(b * 256 + lane * 4 + u) * 4096 + x];
        int m = xn[t];
        double best = 1e300; int bi = IBIG;
        for (int c = 0; c < m; ++c) {
            int j = xlist[t * 8 + c];
            float4 e = ((const float4*)emb)[(size_t)j * 64 + lane];
            double d = zz[0] * (double)e.x + zz[1] * (double)e.y
                     + zz[2] * (double)e.z + zz[3] * (double)e.w;
            #pragma unroll
            for (int off = 32; off; off >>= 1) d += __shfl_down(d, off, 64);
            double s = enorm64[j] - 2.0 * d;   // valid on lane 0
            if (s < best || (s == best && j < bi)) { best = s; bi = j; }
        }
        if (lane == 0) {
            int old = idx32[t];
            if (bi != old) {
                idx32[t] = bi;
                out_idx[t] = (float)bi;
                atomicSub(&cnt[old], 1);
                atomicAdd(&cnt[bi], 1);
            }
        }
    }
}

// ---------------- fp64 full-row recheck (rare fallback) ----------------
__global__ void k_recheck(const float* __restrict__ z, const float* __restrict__ emb,
                          const double* __restrict__ enorm64,
                          const int* __restrict__ flagList, const int* __restrict__ flagCount,
                          int* __restrict__ idx32, int* __restrict__ cnt,
                          float* __restrict__ out_idx) {
    __shared__ float zrow[E_DIM];
    __shared__ double rv[1024];
    __shared__ int ri[1024];
    const int tid = threadIdx.x;
    const int nf = *flagCount;
    for (int f = blockIdx.x; f < nf; f += gridDim.x) {
        const int t = flagList[f];
        const int b = t >> 12, x = t & 4095;
        __syncthreads();
        if (tid < E_DIM) zrow[tid] = z[(size_t)(b * 256 + tid) * 4096 + x];
        __syncthreads();
        double best = 1e300; int bi = IBIG;
        for (int s = 0; s < N_E / 1024; s++) {
            int j = s * 1024 + tid;
            const float4* er4 = (const float4*)(emb + (size_t)j * E_DIM);
            double a0 = 0.0, a1 = 0.0, a2 = 0.0, a3 = 0.0;
            for (int k4 = 0; k4 < 64; ++k4) {
                float4 e = er4[k4];
                a0 = fma((double)e.x, (double)zrow[k4 * 4 + 0], a0);
                a1 = fma((double)e.y, (double)zrow[k4 * 4 + 1], a1);
                a2 = fma((double)e.z, (double)zrow[k4 * 4 + 2], a2);
                a3 = fma((double)e.w, (double)zrow[k4 * 4 + 3], a3);
            }
            double d = enorm64[j] - 2.0 * ((a0 + a1) + (a2 + a3));
            if (d < best || (d == best && j < bi)) { best = d; bi = j; }
        }
        rv[tid] = best; ri[tid] = bi;
        __syncthreads();
        for (int off = 512; off; off >>= 1) {
            if (tid < off) {
                if (rv[tid + off] < rv[tid] ||
                    (rv[tid + off] == rv[tid] && ri[tid + off] < ri[tid])) {
                    rv[tid] = rv[tid + off]; ri[tid] = ri[tid + off];
                }
            }
            __syncthreads();
        }
        if (tid == 0) {
            int old = idx32[t];
            int nw = ri[0];
            if (nw != old) {
                idx32[t] = nw;
                out_idx[t] = (float)nw;
                atomicSub(&cnt[old], 1);
                atomicAdd(&cnt[nw], 1);
            }
        }
        __syncthreads();
    }
}

// ---------------- exclusive scan of cnt[4096] + n/usage stats ----------------
__global__ void k_scan(const int* __restrict__ cnt, int* __restrict__ offs,
                       const float* __restrict__ cluster_size,
                       float* __restrict__ nval, float* __restrict__ out_usage) {
    __shared__ int sc[1024];
    __shared__ float sn[1024];
    __shared__ float su[1024];
    int tid = threadIdx.x;
    int c0 = cnt[tid * 4], c1 = cnt[tid * 4 + 1], c2 = cnt[tid * 4 + 2], c3 = cnt[tid * 4 + 3];
    int ls = c0 + c1 + c2 + c3;
    float ns = 0.f, us = 0.f;
    {
        int cc[4] = {c0, c1, c2, c3};
        #pragma unroll
        for (int u = 0; u < 4; ++u) {
            ns += cluster_size[tid * 4 + u] * DECAY + (1.f - DECAY) * (float)cc[u];
            us += (cc[u] > 0) ? 1.f : 0.f;
        }
    }
    sc[tid] = ls; sn[tid] = ns; su[tid] = us;
    __syncthreads();
    for (int off = 1; off < 1024; off <<= 1) {
        int v = (tid >= off) ? sc[tid - off] : 0;
        __syncthreads();
        sc[tid] += v;
        __syncthreads();
    }
    int base = sc[tid] - ls;
    offs[tid * 4] = base;
    offs[tid * 4 + 1] = base + c0;
    offs[tid * 4 + 2] = base + c0 + c1;
    offs[tid * 4 + 3] = base + c0 + c1 + c2;
    for (int off = 512; off; off >>= 1) {
        if (tid < off) { sn[tid] += sn[tid + off]; su[tid] += su[tid + off]; }
        __syncthreads();
    }
    if (tid == 0) { *nval = sn[0]; *out_usage = su[0] / (float)N_E; }
}

// ---------------- place tokens into per-code lists ----------------
__global__ void k_place(const int* __restrict__ idx32, int* __restrict__ offs,
                        int* __restrict__ tokList) {
    int t = blockIdx.x * blockDim.x + threadIdx.x;
    if (t >= NTOK) return;
    int j = idx32[t];
    int p = atomicAdd(&offs[j], 1);
    tokList[p] = t;
}

// ---------------- dw: per-code coalesced reduction, 4 lane-groups ----------------
__global__ void k_dw(const unsigned short* __restrict__ zh,
                     const int* __restrict__ cnt, const int* __restrict__ offs,
                     const int* __restrict__ tokList, float* __restrict__ dw) {
    __shared__ float red[4][256];
    int j = blockIdx.x;
    int g = threadIdx.x >> 6;
    int lane = threadIdx.x & 63;
    int n = cnt[j];
    int s0 = offs[j] - n;     // offs holds end positions after k_place
    float4 acc = make_float4(0.f, 0.f, 0.f, 0.f);
    for (int i = g; i < n; i += 4) {
        int t = tokList[s0 + i];
        ushort4 h = *(const ushort4*)&zh[(size_t)t * 256 + lane * 4];
        acc.x += h2f(h.x);
        acc.y += h2f(h.y);
        acc.z += h2f(h.z);
        acc.w += h2f(h.w);
    }
    red[g][lane * 4 + 0] = acc.x; red[g][lane * 4 + 1] = acc.y;
    red[g][lane * 4 + 2] = acc.z; red[g][lane * 4 + 3] = acc.w;
    __syncthreads();
    if (g == 0) {
        #pragma unroll
        for (int u = 0; u < 4; ++u) {
            int c = lane * 4 + u;
            dw[(size_t)j * 256 + c] = red[0][c] + red[1][c] + red[2][c] + red[3][c];
        }
    }
}

// ---------------- zq gather ----------------
__global__ void k_zq(const float* __restrict__ emb, const int* __restrict__ idx32,
                     float* __restrict__ out_zq) {
    int t = blockIdx.x * blockDim.x + threadIdx.x;
    int j = idx32[t];
    int b = t >> 12, x = t & 4095;
    const float4* er = (const float4*)(emb + (size_t)j * E_DIM);
    float* ob = out_zq + (size_t)b * (E_DIM * ZX) + x;
    #pragma unroll 8
    for (int c4 = 0; c4 < E_DIM / 4; c4++) {
        float4 v = er[c4];
        ob[(size_t)(c4 * 4 + 0) * ZX] = v.x;
        ob[(size_t)(c4 * 4 + 1) * ZX] = v.y;
        ob[(size_t)(c4 * 4 + 2) * ZX] = v.z;
        ob[(size_t)(c4 * 4 + 3) * ZX] = v.w;
    }
}

// ---------------- EMA epilogue ----------------
__global__ void k_final(const float* __restrict__ cluster_size, const int* __restrict__ cnt,
                        const float* __restrict__ emb_avg, const float* __restrict__ dw,
                        const float* __restrict__ nval,
                        float* __restrict__ out_cluster, float* __restrict__ out_avg,
                        float* __restrict__ out_embed) {
    int j = blockIdx.x;
    int k = threadIdx.x;
    float nc = cluster_size[j] * DECAY + (1.f - DECAY) * (float)cnt[j];
    float n = *nval;
    float cs = (nc + EPSV) / (n + (float)N_E * EPSV) * n;
    float na = emb_avg[(size_t)j * E_DIM + k] * DECAY + (1.f - DECAY) * dw[(size_t)j * E_DIM + k];
    out_avg[(size_t)j * E_DIM + k] = na;
    out_embed[(size_t)j * E_DIM + k] = na / cs;
    if (k == 0) out_cluster[j] = nc;
}

extern "C" void kernel_launch(void* const* d_in, const int* in_sizes, int n_in,
                              void* d_out, int out_size, void* d_ws, size_t ws_size,
                              hipStream_t stream) {
    const float* z            = (const float*)d_in[0];
    const float* emb          = (const float*)d_in[1];
    const float* cluster_size = (const float*)d_in[2];
    const float* emb_avg      = (const float*)d_in[3];
    float* out = (float*)d_out;

    // ---- d_ws layout (bytes), ~18.5 MB ----
    char* ws = (char*)d_ws;
    unsigned short* zh   = (unsigned short*)(ws + 0);          // 16,777,216 (f16)
    float* enorm32       = (float*)(ws + 16777216);            // 16,384
    double* enorm64      = (double*)(ws + 16793600);           // 32,768
    int* idx32           = (int*)(ws + 16826368);              // 131,072
    int* flagList        = (int*)(ws + 16957440);              // 131,072
    int* flagList2       = (int*)(ws + 17088512);              // 131,072
    int* xlist           = (int*)(ws + 17219584);              // 1,048,576
    int* xn              = (int*)(ws + 18268160);              // 131,072
    int* cnt             = (int*)(ws + 18399232);              // 16,384
    int* offs            = (int*)(ws + 18415616);              // 16,384
    int* flagCnt         = (int*)(ws + 18432000);              // 64
    int* flagCnt2        = (int*)(ws + 18432064);              // 64
    float* nval          = (float*)(ws + 18432128);            // 64

    // ---- scratch inside d_out's zq region (zq written last) ----
    unsigned* pk1        = (unsigned*)(out + 0);        // 8 MB
    unsigned* pk2        = (unsigned*)(out + 2097152);  // 8 MB
    unsigned* pk3        = (unsigned*)(out + 4194304);  // 8 MB
    float* dw            = out + 6291456;               // 4 MB
    unsigned short* Bp   = (unsigned short*)(out + 7340032);   // 2 MB
    int*   tokList       = (int*)(out + 7864320);       // 128 KB (ends 7,897,088)

    // ---- output sections ----
    float* out_zq      = out + 0;
    float* out_idx     = out + 8388608;
    float* out_cluster = out + 8421376;
    float* out_avg     = out + 8425472;
    float* out_embed   = out + 9474048;
    float* out_usage   = out + 10522624;

    hipLaunchKernelGGL(k_prep_z, dim3(2048), dim3(256), 0, stream, z, zh);
    hipLaunchKernelGGL(k_prep_e, dim3(1024), dim3(256), 0, stream, emb, Bp, enorm32, enorm64,
                       cnt, flagCnt, flagCnt2);
    hipLaunchKernelGGL(k_dist,   dim3(256, NJB), dim3(256), 0, stream,
                       zh, Bp, enorm32, pk1, pk2, pk3);
    hipLaunchKernelGGL(k_merge,  dim3(128), dim3(256), 0, stream,
                       pk1, pk2, pk3, idx32, cnt, out_idx,
                       xlist, xn, flagList, flagCnt, flagList2, flagCnt2);
    hipLaunchKernelGGL(k_tri,    dim3(512), dim3(256), 0, stream,
                       z, emb, enorm64, flagList, flagCnt, xlist, xn, idx32, cnt, out_idx);
    hipLaunchKernelGGL(k_recheck, dim3(512), dim3(1024), 0, stream,
                       z, emb, enorm64, flagList2, flagCnt2, idx32, cnt, out_idx);
    hipLaunchKernelGGL(k_scan,   dim3(1), dim3(1024), 0, stream, cnt, offs,
                       cluster_size, nval, out_usage);
    hipLaunchKernelGGL(k_place,  dim3(128), dim3(256), 0, stream, idx32, offs, tokList);
    hipLaunchKernelGGL(k_dw,     dim3(4096), dim3(256), 0, stream, zh, cnt, offs, tokList, dw);
    hipLaunchKernelGGL(k_final,  dim3(4096), dim3(256), 0, stream,
                       cluster_size, cnt, emb_avg, dw, nval,
                       out_cluster, out_avg, out_embed);
    hipLaunchKernelGGL(k_zq,     dim3(128), dim3(256), 0, stream, emb, idx32, out_zq);
}

// Round 9
// 276.397 us; speedup vs baseline: 3.1135x; 1.0641x over previous
//
#include <hip/hip_runtime.h>

#define N_E   4096
#define E_DIM 256
#define NTOK  32768
#define ZX    4096
#define DECAY 0.99f
#define EPSV  1e-5f
#define TAU   0.3f
#define NJB   32        // N_E / 128 j-blocks
#define NHALF 64        // 64-col halves
#define IBIG  0x7fffffff

typedef _Float16 half8 __attribute__((ext_vector_type(8)));
typedef __attribute__((ext_vector_type(4))) float f32x4;

__device__ __forceinline__ unsigned short f2h(float x) {
    _Float16 h = (_Float16)x;
    unsigned short u;
    __builtin_memcpy(&u, &h, 2);
    return u;
}
__device__ __forceinline__ float h2f(unsigned short u) {
    _Float16 h;
    __builtin_memcpy(&h, &u, 2);
    return (float)h;
}
__device__ __forceinline__ unsigned umin2(unsigned a, unsigned b) { return a < b ? a : b; }
__device__ __forceinline__ unsigned umax2(unsigned a, unsigned b) { return a > b ? a : b; }
__device__ __forceinline__ void gload16(const void* g, void* l) {
    __builtin_amdgcn_global_load_lds(
        (const __attribute__((address_space(1))) char*)g,
        (__attribute__((address_space(3))) char*)l, 16, 0, 0);
}

// ---------------- prep z: (b,c,x) fp32 -> zh [t][c] f16 ----------------
__global__ void k_prep_z(const float* __restrict__ z, unsigned short* __restrict__ zh) {
    __shared__ float lt[64][65];
    const int bid = blockIdx.x;
    const int xt = bid & 63, ct = (bid >> 6) & 3, b = bid >> 8;
    const int tid = threadIdx.x;
    #pragma unroll
    for (int r = 0; r < 4; ++r) {
        int cy = r * 16 + (tid >> 4);
        int xx4 = tid & 15;
        float4 v = ((const float4*)z)[(size_t)(b * 256 + ct * 64 + cy) * 1024 + xt * 16 + xx4];
        lt[cy][xx4 * 4 + 0] = v.x; lt[cy][xx4 * 4 + 1] = v.y;
        lt[cy][xx4 * 4 + 2] = v.z; lt[cy][xx4 * 4 + 3] = v.w;
    }
    __syncthreads();
    #pragma unroll
    for (int it = 0; it < 2; ++it) {
        int tl = it * 32 + (tid >> 3);
        int c8 = tid & 7;
        unsigned short h[8];
        #pragma unroll
        for (int u = 0; u < 8; ++u) h[u] = f2h(lt[c8 * 8 + u][tl]);
        size_t t = (size_t)(b * 4096 + xt * 64 + tl);
        size_t o = t * 256 + ct * 64 + c8 * 8;
        *(ushort4*)&zh[o]     = make_ushort4(h[0], h[1], h[2], h[3]);
        *(ushort4*)&zh[o + 4] = make_ushort4(h[4], h[5], h[6], h[7]);
    }
}

// ---------------- prep emb: Bp = e (f16), enorm32/64; fused init ----------------
__global__ void k_prep_e(const float* __restrict__ emb, unsigned short* __restrict__ Bp,
                         float* __restrict__ enorm32, double* __restrict__ enorm64,
                         int* __restrict__ cnt, int* __restrict__ flagCnt,
                         int* __restrict__ flagCnt2) {
    if (threadIdx.x < 4) cnt[blockIdx.x * 4 + threadIdx.x] = 0;
    if (blockIdx.x == 0 && threadIdx.x == 0) { *flagCnt = 0; *flagCnt2 = 0; }
    int j = blockIdx.x * 4 + (threadIdx.x >> 6);
    int lane = threadIdx.x & 63;
    float4 v = ((const float4*)emb)[(size_t)j * 64 + lane];
    float f[4] = {v.x, v.y, v.z, v.w};
    unsigned short h[4];
    #pragma unroll
    for (int u = 0; u < 4; ++u) h[u] = f2h(f[u]);
    *(ushort4*)&Bp[(size_t)j * E_DIM + lane * 4] = make_ushort4(h[0], h[1], h[2], h[3]);
    double s = 0.0;
    #pragma unroll
    for (int u = 0; u < 4; ++u) s += (double)f[u] * (double)f[u];
    #pragma unroll
    for (int off = 32; off; off >>= 1) s += __shfl_down(s, off, 64);
    if (lane == 0) { enorm32[j] = (float)s; enorm64[j] = s; }
}

// ---------------- MFMA f16 distance; per-half top-3 packed keys (single-buffer) ----------------
__global__ __launch_bounds__(256) void k_dist(
        const unsigned short* __restrict__ zh,
        const unsigned short* __restrict__ Bp, const float* __restrict__ enorm32,
        unsigned* __restrict__ pk1, unsigned* __restrict__ pk2, unsigned* __restrict__ pk3) {
    __shared__ __align__(16) char smem[32768];   // single buffer: 16KB A + 16KB B
    const int tid = threadIdx.x;
    const int lane = tid & 63;
    const int w = tid >> 6;
    const int wr = w >> 1, wc = w & 1;
    const int t0 = blockIdx.x * 128;
    const int jb = blockIdx.y;
    const int j0 = jb * 128;
    const int sw16 = (((lane & 7) ^ (lane >> 3)) << 4);
    const int rowsub = lane >> 3;

    f32x4 acc[4][4];
    #pragma unroll
    for (int m = 0; m < 4; ++m)
        #pragma unroll
        for (int nn = 0; nn < 4; ++nn)
            acc[m][nn] = (f32x4){0.f, 0.f, 0.f, 0.f};

    auto stage = [&](int s) {
        const int kb = s * 128 + sw16;
        #pragma unroll
        for (int c = 0; c < 4; ++c) {
            int seg = w * 4 + c;
            int arow = t0 + seg * 8 + rowsub;
            int brow = j0 + seg * 8 + rowsub;
            gload16((const char*)zh + (size_t)arow * 512 + kb, &smem[seg * 1024]);
            gload16((const char*)Bp + (size_t)brow * 512 + kb, &smem[16384 + seg * 1024]);
        }
    };

    stage(0);
    for (int s = 0; s < 4; ++s) {
        __syncthreads();                 // staged data visible (vmcnt drained)
        const int xr = ((lane & 7) << 4);
        #pragma unroll
        for (int kk = 0; kk < 2; ++kk) {
            const int colb = (kk * 64 + ((lane >> 4) << 4)) ^ xr;
            half8 a[4], b[4];
            #pragma unroll
            for (int m = 0; m < 4; ++m)
                a[m] = *(const half8*)&smem[((wr * 64 + m * 16 + (lane & 15)) << 7) + colb];
            #pragma unroll
            for (int nn = 0; nn < 4; ++nn)
                b[nn] = *(const half8*)&smem[16384 + ((wc * 64 + nn * 16 + (lane & 15)) << 7) + colb];
            // swapped operands: D[row=code, col=token]
            #pragma unroll
            for (int m = 0; m < 4; ++m)
                #pragma unroll
                for (int nn = 0; nn < 4; ++nn)
                    acc[m][nn] = __builtin_amdgcn_mfma_f32_16x16x32_f16(b[nn], a[m], acc[m][nn], 0, 0, 0);
        }
        if (s < 3) {
            __syncthreads();             // all waves done reading -> safe to overwrite
            stage(s + 1);
        }
    }

    // ---- epilogue: per-half top-3 packed u32 keys; 2-pass butterfly ----
    const int g   = lane >> 4;       // code row-group
    const int gg4 = g * 4;
    const int h   = jb * 2 + wc;
    float enb[4][4];
    #pragma unroll
    for (int nn = 0; nn < 4; ++nn) {
        float4 e4 = *(const float4*)&enorm32[j0 + wc * 64 + nn * 16 + gg4];
        enb[nn][0] = e4.x + 4096.f; enb[nn][1] = e4.y + 4096.f;
        enb[nn][2] = e4.z + 4096.f; enb[nn][3] = e4.w + 4096.f;
    }
    unsigned s1 = 0, s2 = 0, s3 = 0;
    #pragma unroll
    for (int m = 0; m < 4; ++m) {
        unsigned k1 = 0xFFFFFFFFu, k2 = 0xFFFFFFFFu, k3 = 0xFFFFFFFFu;
        #pragma unroll
        for (int nn = 0; nn < 4; ++nn)
            #pragma unroll
            for (int r = 0; r < 4; ++r) {
                float sc = fmaf(-2.f, acc[m][nn][r], enb[nn][r]);   // > 0 by construction
                unsigned key = (__float_as_uint(sc) & 0xFFFFFFC0u)
                             | (unsigned)(gg4 + nn * 16 + r);
                k3 = umin2(k3, umax2(k2, key));
                k2 = umin2(k2, umax2(k1, key));
                k1 = umin2(k1, key);
            }
        #pragma unroll
        for (int off = 16; off <= 32; off <<= 1) {
            unsigned b1 = (unsigned)__shfl_xor((int)k1, off, 64);
            unsigned b2 = (unsigned)__shfl_xor((int)k2, off, 64);
            unsigned b3 = (unsigned)__shfl_xor((int)k3, off, 64);
            unsigned p  = umax2(k1, b1);
            unsigned q  = umin2(k2, b2);
            unsigned r2 = umax2(k2, b2);
            unsigned ss = umin2(k3, b3);
            k1 = umin2(k1, b1);
            k2 = umin2(p, q);
            k3 = umin2(umax2(p, q), umin2(r2, ss));
        }
        s1 = (g == m) ? k1 : s1;
        s2 = (g == m) ? k2 : s2;
        s3 = (g == m) ? k3 : s3;
    }
    size_t o = (size_t)h * NTOK + t0 + wr * 64 + lane;
    pk1[o] = s1; pk2[o] = s2; pk3[o] = s3;
}

// ---------------- merge halves on keys, histogram, candidate collection ----------------
__global__ void k_merge(const unsigned* __restrict__ pk1, const unsigned* __restrict__ pk2,
                        const unsigned* __restrict__ pk3,
                        int* __restrict__ idx32, int* __restrict__ cnt,
                        float* __restrict__ out_idx,
                        int* __restrict__ xlist, int* __restrict__ xn,
                        int* __restrict__ flagList, int* __restrict__ flagCount,
                        int* __restrict__ flagList2, int* __restrict__ flagCount2) {
    int t = blockIdx.x * blockDim.x + threadIdx.x;
    if (t >= NTOK) return;
    unsigned g1 = 0xFFFFFFFFu, g2 = 0xFFFFFFFFu;
    int h1 = 0;
    for (int s = 0; s < NHALF; s++) {
        unsigned a = pk1[(size_t)s * NTOK + t];
        unsigned b = pk2[(size_t)s * NTOK + t];
        bool c = a < g1;
        g2 = c ? g1 : umin2(g2, a);
        h1 = c ? s : h1;
        g1 = c ? a : g1;
        g2 = umin2(g2, b);          // b >= a so never the global min
    }
    int x1 = h1 * 64 + (int)(g1 & 63u);
    idx32[t] = x1;
    atomicAdd(&cnt[x1], 1);
    out_idx[t] = (float)x1;
    float v1 = __uint_as_float(g1 & 0xFFFFFFC0u);
    float v2 = __uint_as_float(g2 & 0xFFFFFFC0u);
    if (v2 - v1 >= TAU) return;     // winner certain at fp16 precision
    unsigned thrk = __float_as_uint(v1 + TAU) | 63u;
    int nc = 0; bool full = false;
    for (int s = 0; s < NHALF; s++) {
        unsigned a = pk1[(size_t)s * NTOK + t];
        if (a > thrk) continue;
        if (pk3[(size_t)s * NTOK + t] <= thrk) { full = true; break; }  // >=3 in band
        if (nc == 8) { full = true; break; }
        xlist[t * 8 + nc++] = s * 64 + (int)(a & 63u);
        unsigned b = pk2[(size_t)s * NTOK + t];
        if (b <= thrk) {
            if (nc == 8) { full = true; break; }
            xlist[t * 8 + nc++] = s * 64 + (int)(b & 63u);
        }
    }
    if (full) {
        int q = atomicAdd(flagCount2, 1);
        flagList2[q] = t;
    } else {
        xn[t] = nc;
        int q = atomicAdd(flagCount, 1);
        flagList[q] = t;
    }
}

// ---------------- exact fp64 referee over candidate list ----------------
__global__ void k_tri(const float* __restrict__ z, const float* __restrict__ emb,
                      const double* __restrict__ enorm64,
                      const int* __restrict__ flagList, const int* __restrict__ flagCount,
                      const int* __restrict__ xlist, const int* __restrict__ xn,
                      int* __restrict__ idx32, int* __restrict__ cnt,
                      float* __restrict__ out_idx) {
    const int lane = threadIdx.x & 63;
    const int wid = blockIdx.x * (blockDim.x >> 6) + (threadIdx.x >> 6);
    const int nw = gridDim.x * (blockDim.x >> 6);
    const int nf = *flagCount;
    for (int f = wid; f < nf; f += nw) {
        int t = flagList[f];
        int b = t >> 12, x = t & 4095;
        double zz[4];
        #pragma unroll
        for (int u = 0; u < 4; ++u)
            zz[u] = (double)z[(size_t)(b * 256 + lane * 4 + u) * 4096 + x];
        int m = xn[t];
        double best = 1e300; int bi = IBIG;
        for (int c = 0; c < m; ++c) {
            int j = xlist[t * 8 + c];
            float4 e = ((const float4*)emb)[(size_t)j * 64 + lane];
            double d = zz[0] * (double)e.x + zz[1] * (double)e.y
                     + zz[2] * (double)e.z + zz[3] * (double)e.w;
            #pragma unroll
            for (int off = 32; off; off >>= 1) d += __shfl_down(d, off, 64);
            double s = enorm64[j] - 2.0 * d;   // valid on lane 0
            if (s < best || (s == best && j < bi)) { best = s; bi = j; }
        }
        if (lane == 0) {
            int old = idx32[t];
            if (bi != old) {
                idx32[t] = bi;
                out_idx[t] = (float)bi;
                atomicSub(&cnt[old], 1);
                atomicAdd(&cnt[bi], 1);
            }
        }
    }
}

// ---------------- fp64 full-row recheck (rare fallback) ----------------
__global__ void k_recheck(const float* __restrict__ z, const float* __restrict__ emb,
                          const double* __restrict__ enorm64,
                          const int* __restrict__ flagList, const int* __restrict__ flagCount,
                          int* __restrict__ idx32, int* __restrict__ cnt,
                          float* __restrict__ out_idx) {
    __shared__ float zrow[E_DIM];
    __shared__ double rv[1024];
    __shared__ int ri[1024];
    const int tid = threadIdx.x;
    const int nf = *flagCount;
    for (int f = blockIdx.x; f < nf; f += gridDim.x) {
        const int t = flagList[f];
        const int b = t >> 12, x = t & 4095;
        __syncthreads();
        if (tid < E_DIM) zrow[tid] = z[(size_t)(b * 256 + tid) * 4096 + x];
        __syncthreads();
        double best = 1e300; int bi = IBIG;
        for (int s = 0; s < N_E / 1024; s++) {
            int j = s * 1024 + tid;
            const float4* er4 = (const float4*)(emb + (size_t)j * E_DIM);
            double a0 = 0.0, a1 = 0.0, a2 = 0.0, a3 = 0.0;
            for (int k4 = 0; k4 < 64; ++k4) {
                float4 e = er4[k4];
                a0 = fma((double)e.x, (double)zrow[k4 * 4 + 0], a0);
                a1 = fma((double)e.y, (double)zrow[k4 * 4 + 1], a1);
                a2 = fma((double)e.z, (double)zrow[k4 * 4 + 2], a2);
                a3 = fma((double)e.w, (double)zrow[k4 * 4 + 3], a3);
            }
            double d = enorm64[j] - 2.0 * ((a0 + a1) + (a2 + a3));
            if (d < best || (d == best && j < bi)) { best = d; bi = j; }
        }
        rv[tid] = best; ri[tid] = bi;
        __syncthreads();
        for (int off = 512; off; off >>= 1) {
            if (tid < off) {
                if (rv[tid + off] < rv[tid] ||
                    (rv[tid + off] == rv[tid] && ri[tid + off] < ri[tid])) {
                    rv[tid] = rv[tid + off]; ri[tid] = ri[tid + off];
                }
            }
            __syncthreads();
        }
        if (tid == 0) {
            int old = idx32[t];
            int nw = ri[0];
            if (nw != old) {
                idx32[t] = nw;
                out_idx[t] = (float)nw;
                atomicSub(&cnt[old], 1);
                atomicAdd(&cnt[nw], 1);
            }
        }
        __syncthreads();
    }
}

// ---------------- exclusive scan of cnt[4096] + n/usage stats ----------------
__global__ void k_scan(const int* __restrict__ cnt, int* __restrict__ offs,
                       const float* __restrict__ cluster_size,
                       float* __restrict__ nval, float* __restrict__ out_usage) {
    __shared__ int sc[1024];
    __shared__ float sn[1024];
    __shared__ float su[1024];
    int tid = threadIdx.x;
    int c0 = cnt[tid * 4], c1 = cnt[tid * 4 + 1], c2 = cnt[tid * 4 + 2], c3 = cnt[tid * 4 + 3];
    int ls = c0 + c1 + c2 + c3;
    float ns = 0.f, us = 0.f;
    {
        int cc[4] = {c0, c1, c2, c3};
        #pragma unroll
        for (int u = 0; u < 4; ++u) {
            ns += cluster_size[tid * 4 + u] * DECAY + (1.f - DECAY) * (float)cc[u];
            us += (cc[u] > 0) ? 1.f : 0.f;
        }
    }
    sc[tid] = ls; sn[tid] = ns; su[tid] = us;
    __syncthreads();
    for (int off = 1; off < 1024; off <<= 1) {
        int v = (tid >= off) ? sc[tid - off] : 0;
        __syncthreads();
        sc[tid] += v;
        __syncthreads();
    }
    int base = sc[tid] - ls;
    offs[tid * 4] = base;
    offs[tid * 4 + 1] = base + c0;
    offs[tid * 4 + 2] = base + c0 + c1;
    offs[tid * 4 + 3] = base + c0 + c1 + c2;
    for (int off = 512; off; off >>= 1) {
        if (tid < off) { sn[tid] += sn[tid + off]; su[tid] += su[tid + off]; }
        __syncthreads();
    }
    if (tid == 0) { *nval = sn[0]; *out_usage = su[0] / (float)N_E; }
}

// ---------------- place tokens into per-code lists ----------------
__global__ void k_place(const int* __restrict__ idx32, int* __restrict__ offs,
                        int* __restrict__ tokList) {
    int t = blockIdx.x * blockDim.x + threadIdx.x;
    if (t >= NTOK) return;
    int j = idx32[t];
    int p = atomicAdd(&offs[j], 1);
    tokList[p] = t;
}

// ---------------- fused dw reduction + EMA epilogue ----------------
__global__ void k_dwfinal(const unsigned short* __restrict__ zh,
                          const int* __restrict__ cnt, const int* __restrict__ offs,
                          const int* __restrict__ tokList,
                          const float* __restrict__ cluster_size,
                          const float* __restrict__ emb_avg, const float* __restrict__ nval,
                          float* __restrict__ out_cluster, float* __restrict__ out_avg,
                          float* __restrict__ out_embed) {
    __shared__ float red[4][256];
    int j = blockIdx.x;
    int g = threadIdx.x >> 6;
    int lane = threadIdx.x & 63;
    int n = cnt[j];
    int s0 = offs[j] - n;     // offs holds end positions after k_place
    float4 acc = make_float4(0.f, 0.f, 0.f, 0.f);
    for (int i = g; i < n; i += 4) {
        int t = tokList[s0 + i];
        ushort4 h = *(const ushort4*)&zh[(size_t)t * 256 + lane * 4];
        acc.x += h2f(h.x);
        acc.y += h2f(h.y);
        acc.z += h2f(h.z);
        acc.w += h2f(h.w);
    }
    red[g][lane * 4 + 0] = acc.x; red[g][lane * 4 + 1] = acc.y;
    red[g][lane * 4 + 2] = acc.z; red[g][lane * 4 + 3] = acc.w;
    __syncthreads();
    if (g == 0) {
        float nc = cluster_size[j] * DECAY + (1.f - DECAY) * (float)n;
        float nv = *nval;
        float cs = (nc + EPSV) / (nv + (float)N_E * EPSV) * nv;
        float4 ea = ((const float4*)emb_avg)[(size_t)j * 64 + lane];
        float4 na, ne;
        na.x = ea.x * DECAY + (1.f - DECAY) * (red[0][lane*4+0] + red[1][lane*4+0] + red[2][lane*4+0] + red[3][lane*4+0]);
        na.y = ea.y * DECAY + (1.f - DECAY) * (red[0][lane*4+1] + red[1][lane*4+1] + red[2][lane*4+1] + red[3][lane*4+1]);
        na.z = ea.z * DECAY + (1.f - DECAY) * (red[0][lane*4+2] + red[1][lane*4+2] + red[2][lane*4+2] + red[3][lane*4+2]);
        na.w = ea.w * DECAY + (1.f - DECAY) * (red[0][lane*4+3] + red[1][lane*4+3] + red[2][lane*4+3] + red[3][lane*4+3]);
        ne.x = na.x / cs; ne.y = na.y / cs; ne.z = na.z / cs; ne.w = na.w / cs;
        ((float4*)out_avg)[(size_t)j * 64 + lane] = na;
        ((float4*)out_embed)[(size_t)j * 64 + lane] = ne;
        if (lane == 0) out_cluster[j] = nc;
    }
}

// ---------------- zq gather (vectorized: 4-token float4 writes) ----------------
__global__ void k_zq(const float* __restrict__ emb, const int* __restrict__ idx32,
                     float* __restrict__ out_zq) {
    int t0 = blockIdx.x * 16;            // 2048 blocks x 16 tokens
    int b = t0 >> 12, x0 = t0 & 4095;
    int c4 = threadIdx.x >> 2;           // 0..63
    int xq = threadIdx.x & 3;            // 0..3
    int jj[4];
    #pragma unroll
    for (int i = 0; i < 4; ++i) jj[i] = idx32[t0 + xq * 4 + i];
    float4 e[4];
    #pragma unroll
    for (int i = 0; i < 4; ++i)
        e[i] = ((const float4*)emb)[(size_t)jj[i] * 64 + c4];
    float* ob = out_zq + (size_t)b * (E_DIM * ZX) + x0 + xq * 4;
    {
        float4 v = make_float4(e[0].x, e[1].x, e[2].x, e[3].x);
        *(float4*)&ob[(size_t)(c4 * 4 + 0) * ZX] = v;
    }
    {
        float4 v = make_float4(e[0].y, e[1].y, e[2].y, e[3].y);
        *(float4*)&ob[(size_t)(c4 * 4 + 1) * ZX] = v;
    }
    {
        float4 v = make_float4(e[0].z, e[1].z, e[2].z, e[3].z);
        *(float4*)&ob[(size_t)(c4 * 4 + 2) * ZX] = v;
    }
    {
        float4 v = make_float4(e[0].w, e[1].w, e[2].w, e[3].w);
        *(float4*)&ob[(size_t)(c4 * 4 + 3) * ZX] = v;
    }
}

extern "C" void kernel_launch(void* const* d_in, const int* in_sizes, int n_in,
                              void* d_out, int out_size, void* d_ws, size_t ws_size,
                              hipStream_t stream) {
    const float* z            = (const float*)d_in[0];
    const float* emb          = (const float*)d_in[1];
    const float* cluster_size = (const float*)d_in[2];
    const float* emb_avg      = (const float*)d_in[3];
    float* out = (float*)d_out;

    // ---- d_ws layout (bytes), ~18.5 MB ----
    char* ws = (char*)d_ws;
    unsigned short* zh   = (unsigned short*)(ws + 0);          // 16,777,216 (f16)
    float* enorm32       = (float*)(ws + 16777216);            // 16,384
    double* enorm64      = (double*)(ws + 16793600);           // 32,768
    int* idx32           = (int*)(ws + 16826368);              // 131,072
    int* flagList        = (int*)(ws + 16957440);              // 131,072
    int* flagList2       = (int*)(ws + 17088512);              // 131,072
    int* xlist           = (int*)(ws + 17219584);              // 1,048,576
    int* xn              = (int*)(ws + 18268160);              // 131,072
    int* cnt             = (int*)(ws + 18399232);              // 16,384
    int* offs            = (int*)(ws + 18415616);              // 16,384
    int* flagCnt         = (int*)(ws + 18432000);              // 64
    int* flagCnt2        = (int*)(ws + 18432064);              // 64
    float* nval          = (float*)(ws + 18432128);            // 64

    // ---- scratch inside d_out's zq region (zq written last) ----
    unsigned* pk1        = (unsigned*)(out + 0);        // 8 MB
    unsigned* pk2        = (unsigned*)(out + 2097152);  // 8 MB
    unsigned* pk3        = (unsigned*)(out + 4194304);  // 8 MB
    unsigned short* Bp   = (unsigned short*)(out + 7340032);   // 2 MB
    int*   tokList       = (int*)(out + 7864320);       // 128 KB (ends 7,897,088)

    // ---- output sections ----
    float* out_zq      = out + 0;
    float* out_idx     = out + 8388608;
    float* out_cluster = out + 8421376;
    float* out_avg     = out + 8425472;
    float* out_embed   = out + 9474048;
    float* out_usage   = out + 10522624;

    hipLaunchKernelGGL(k_prep_z, dim3(2048), dim3(256), 0, stream, z, zh);
    hipLaunchKernelGGL(k_prep_e, dim3(1024), dim3(256), 0, stream, emb, Bp, enorm32, enorm64,
                       cnt, flagCnt, flagCnt2);
    hipLaunchKernelGGL(k_dist,   dim3(256, NJB), dim3(256), 0, stream,
                       zh, Bp, enorm32, pk1, pk2, pk3);
    hipLaunchKernelGGL(k_merge,  dim3(128), dim3(256), 0, stream,
                       pk1, pk2, pk3, idx32, cnt, out_idx,
                       xlist, xn, flagList, flagCnt, flagList2, flagCnt2);
    hipLaunchKernelGGL(k_tri,    dim3(512), dim3(256), 0, stream,
                       z, emb, enorm64, flagList, flagCnt, xlist, xn, idx32, cnt, out_idx);
    hipLaunchKernelGGL(k_recheck, dim3(128), dim3(1024), 0, stream,
                       z, emb, enorm64, flagList2, flagCnt2, idx32, cnt, out_idx);
    hipLaunchKernelGGL(k_scan,   dim3(1), dim3(1024), 0, stream, cnt, offs,
                       cluster_size, nval, out_usage);
    hipLaunchKernelGGL(k_place,  dim3(128), dim3(256), 0, stream, idx32, offs, tokList);
    hipLaunchKernelGGL(k_dwfinal, dim3(4096), dim3(256), 0, stream,
                       zh, cnt, offs, tokList, cluster_size, emb_avg, nval,
                       out_cluster, out_avg, out_embed);
    hipLaunchKernelGGL(k_zq,     dim3(2048), dim3(256), 0, stream, emb, idx32, out_zq);
}

// Round 10
// 201.748 us; speedup vs baseline: 4.2655x; 1.3700x over previous
//
#include <hip/hip_runtime.h>

#define N_E   4096
#define E_DIM 256
#define NTOK  32768
#define ZX    4096
#define DECAY 0.99f
#define EPSV  1e-5f
#define TAU   0.3f
#define NJB   32        // N_E / 128 j-blocks
#define NHALF 64        // 64-col halves
#define NSPL  4         // dw splits per code
#define IBIG  0x7fffffff

typedef _Float16 half8 __attribute__((ext_vector_type(8)));
typedef __attribute__((ext_vector_type(4))) float f32x4;

__device__ __forceinline__ unsigned short f2h(float x) {
    _Float16 h = (_Float16)x;
    unsigned short u;
    __builtin_memcpy(&u, &h, 2);
    return u;
}
__device__ __forceinline__ float h2f(unsigned short u) {
    _Float16 h;
    __builtin_memcpy(&h, &u, 2);
    return (float)h;
}
__device__ __forceinline__ unsigned umin2(unsigned a, unsigned b) { return a < b ? a : b; }
__device__ __forceinline__ unsigned umax2(unsigned a, unsigned b) { return a > b ? a : b; }
__device__ __forceinline__ void gload16(const void* g, void* l) {
    __builtin_amdgcn_global_load_lds(
        (const __attribute__((address_space(1))) char*)g,
        (__attribute__((address_space(3))) char*)l, 16, 0, 0);
}

// ---------------- prep z: (b,c,x) fp32 -> zh [t][c] f16 ----------------
__global__ void k_prep_z(const float* __restrict__ z, unsigned short* __restrict__ zh) {
    __shared__ float lt[64][65];
    const int bid = blockIdx.x;
    const int xt = bid & 63, ct = (bid >> 6) & 3, b = bid >> 8;
    const int tid = threadIdx.x;
    #pragma unroll
    for (int r = 0; r < 4; ++r) {
        int cy = r * 16 + (tid >> 4);
        int xx4 = tid & 15;
        float4 v = ((const float4*)z)[(size_t)(b * 256 + ct * 64 + cy) * 1024 + xt * 16 + xx4];
        lt[cy][xx4 * 4 + 0] = v.x; lt[cy][xx4 * 4 + 1] = v.y;
        lt[cy][xx4 * 4 + 2] = v.z; lt[cy][xx4 * 4 + 3] = v.w;
    }
    __syncthreads();
    #pragma unroll
    for (int it = 0; it < 2; ++it) {
        int tl = it * 32 + (tid >> 3);
        int c8 = tid & 7;
        unsigned short h[8];
        #pragma unroll
        for (int u = 0; u < 8; ++u) h[u] = f2h(lt[c8 * 8 + u][tl]);
        size_t t = (size_t)(b * 4096 + xt * 64 + tl);
        size_t o = t * 256 + ct * 64 + c8 * 8;
        *(ushort4*)&zh[o]     = make_ushort4(h[0], h[1], h[2], h[3]);
        *(ushort4*)&zh[o + 4] = make_ushort4(h[4], h[5], h[6], h[7]);
    }
}

// ---------------- prep emb: Bp = e (f16), enorm32/64; fused init ----------------
__global__ void k_prep_e(const float* __restrict__ emb, unsigned short* __restrict__ Bp,
                         float* __restrict__ enorm32, double* __restrict__ enorm64,
                         int* __restrict__ cnt, int* __restrict__ flagCnt,
                         int* __restrict__ flagCnt2) {
    if (threadIdx.x < 4) cnt[blockIdx.x * 4 + threadIdx.x] = 0;
    if (blockIdx.x == 0 && threadIdx.x == 0) { *flagCnt = 0; *flagCnt2 = 0; }
    int j = blockIdx.x * 4 + (threadIdx.x >> 6);
    int lane = threadIdx.x & 63;
    float4 v = ((const float4*)emb)[(size_t)j * 64 + lane];
    float f[4] = {v.x, v.y, v.z, v.w};
    unsigned short h[4];
    #pragma unroll
    for (int u = 0; u < 4; ++u) h[u] = f2h(f[u]);
    *(ushort4*)&Bp[(size_t)j * E_DIM + lane * 4] = make_ushort4(h[0], h[1], h[2], h[3]);
    double s = 0.0;
    #pragma unroll
    for (int u = 0; u < 4; ++u) s += (double)f[u] * (double)f[u];
    #pragma unroll
    for (int off = 32; off; off >>= 1) s += __shfl_down(s, off, 64);
    if (lane == 0) { enorm32[j] = (float)s; enorm64[j] = s; }
}

// ---------------- MFMA f16 distance; per-half top-3 packed keys (single-buffer) ----------------
__global__ __launch_bounds__(256) void k_dist(
        const unsigned short* __restrict__ zh,
        const unsigned short* __restrict__ Bp, const float* __restrict__ enorm32,
        unsigned* __restrict__ pk1, unsigned* __restrict__ pk2, unsigned* __restrict__ pk3) {
    __shared__ __align__(16) char smem[32768];   // single buffer: 16KB A + 16KB B
    const int tid = threadIdx.x;
    const int lane = tid & 63;
    const int w = tid >> 6;
    const int wr = w >> 1, wc = w & 1;
    const int t0 = blockIdx.x * 128;
    const int jb = blockIdx.y;
    const int j0 = jb * 128;
    const int sw16 = (((lane & 7) ^ (lane >> 3)) << 4);
    const int rowsub = lane >> 3;

    f32x4 acc[4][4];
    #pragma unroll
    for (int m = 0; m < 4; ++m)
        #pragma unroll
        for (int nn = 0; nn < 4; ++nn)
            acc[m][nn] = (f32x4){0.f, 0.f, 0.f, 0.f};

    auto stage = [&](int s) {
        const int kb = s * 128 + sw16;
        #pragma unroll
        for (int c = 0; c < 4; ++c) {
            int seg = w * 4 + c;
            int arow = t0 + seg * 8 + rowsub;
            int brow = j0 + seg * 8 + rowsub;
            gload16((const char*)zh + (size_t)arow * 512 + kb, &smem[seg * 1024]);
            gload16((const char*)Bp + (size_t)brow * 512 + kb, &smem[16384 + seg * 1024]);
        }
    };

    stage(0);
    for (int s = 0; s < 4; ++s) {
        __syncthreads();                 // staged data visible (vmcnt drained)
        const int xr = ((lane & 7) << 4);
        #pragma unroll
        for (int kk = 0; kk < 2; ++kk) {
            const int colb = (kk * 64 + ((lane >> 4) << 4)) ^ xr;
            half8 a[4], b[4];
            #pragma unroll
            for (int m = 0; m < 4; ++m)
                a[m] = *(const half8*)&smem[((wr * 64 + m * 16 + (lane & 15)) << 7) + colb];
            #pragma unroll
            for (int nn = 0; nn < 4; ++nn)
                b[nn] = *(const half8*)&smem[16384 + ((wc * 64 + nn * 16 + (lane & 15)) << 7) + colb];
            // swapped operands: D[row=code, col=token]
            #pragma unroll
            for (int m = 0; m < 4; ++m)
                #pragma unroll
                for (int nn = 0; nn < 4; ++nn)
                    acc[m][nn] = __builtin_amdgcn_mfma_f32_16x16x32_f16(b[nn], a[m], acc[m][nn], 0, 0, 0);
        }
        if (s < 3) {
            __syncthreads();             // all waves done reading -> safe to overwrite
            stage(s + 1);
        }
    }

    // ---- epilogue: per-half top-3 packed u32 keys; 2-pass butterfly ----
    const int g   = lane >> 4;       // code row-group
    const int gg4 = g * 4;
    const int h   = jb * 2 + wc;
    float enb[4][4];
    #pragma unroll
    for (int nn = 0; nn < 4; ++nn) {
        float4 e4 = *(const float4*)&enorm32[j0 + wc * 64 + nn * 16 + gg4];
        enb[nn][0] = e4.x + 4096.f; enb[nn][1] = e4.y + 4096.f;
        enb[nn][2] = e4.z + 4096.f; enb[nn][3] = e4.w + 4096.f;
    }
    unsigned s1 = 0, s2 = 0, s3 = 0;
    #pragma unroll
    for (int m = 0; m < 4; ++m) {
        unsigned k1 = 0xFFFFFFFFu, k2 = 0xFFFFFFFFu, k3 = 0xFFFFFFFFu;
        #pragma unroll
        for (int nn = 0; nn < 4; ++nn)
            #pragma unroll
            for (int r = 0; r < 4; ++r) {
                float sc = fmaf(-2.f, acc[m][nn][r], enb[nn][r]);   // > 0 by construction
                unsigned key = (__float_as_uint(sc) & 0xFFFFFFC0u)
                             | (unsigned)(gg4 + nn * 16 + r);
                k3 = umin2(k3, umax2(k2, key));
                k2 = umin2(k2, umax2(k1, key));
                k1 = umin2(k1, key);
            }
        #pragma unroll
        for (int off = 16; off <= 32; off <<= 1) {
            unsigned b1 = (unsigned)__shfl_xor((int)k1, off, 64);
            unsigned b2 = (unsigned)__shfl_xor((int)k2, off, 64);
            unsigned b3 = (unsigned)__shfl_xor((int)k3, off, 64);
            unsigned p  = umax2(k1, b1);
            unsigned q  = umin2(k2, b2);
            unsigned r2 = umax2(k2, b2);
            unsigned ss = umin2(k3, b3);
            k1 = umin2(k1, b1);
            k2 = umin2(p, q);
            k3 = umin2(umax2(p, q), umin2(r2, ss));
        }
        s1 = (g == m) ? k1 : s1;
        s2 = (g == m) ? k2 : s2;
        s3 = (g == m) ? k3 : s3;
    }
    size_t o = (size_t)h * NTOK + t0 + wr * 64 + lane;
    pk1[o] = s1; pk2[o] = s2; pk3[o] = s3;
}

// ---------------- merge halves on keys, histogram, candidate collection ----------------
__global__ void k_merge(const unsigned* __restrict__ pk1, const unsigned* __restrict__ pk2,
                        const unsigned* __restrict__ pk3,
                        int* __restrict__ idx32, int* __restrict__ cnt,
                        float* __restrict__ out_idx,
                        int* __restrict__ xlist, int* __restrict__ xn,
                        int* __restrict__ flagList, int* __restrict__ flagCount,
                        int* __restrict__ flagList2, int* __restrict__ flagCount2) {
    int t = blockIdx.x * blockDim.x + threadIdx.x;
    if (t >= NTOK) return;
    unsigned g1 = 0xFFFFFFFFu, g2 = 0xFFFFFFFFu;
    int h1 = 0;
    for (int s = 0; s < NHALF; s++) {
        unsigned a = pk1[(size_t)s * NTOK + t];
        unsigned b = pk2[(size_t)s * NTOK + t];
        bool c = a < g1;
        g2 = c ? g1 : umin2(g2, a);
        h1 = c ? s : h1;
        g1 = c ? a : g1;
        g2 = umin2(g2, b);          // b >= a so never the global min
    }
    int x1 = h1 * 64 + (int)(g1 & 63u);
    idx32[t] = x1;
    atomicAdd(&cnt[x1], 1);
    out_idx[t] = (float)x1;
    float v1 = __uint_as_float(g1 & 0xFFFFFFC0u);
    float v2 = __uint_as_float(g2 & 0xFFFFFFC0u);
    if (v2 - v1 >= TAU) return;     // winner certain at fp16 precision
    unsigned thrk = __float_as_uint(v1 + TAU) | 63u;
    int nc = 0; bool full = false;
    for (int s = 0; s < NHALF; s++) {
        unsigned a = pk1[(size_t)s * NTOK + t];
        if (a > thrk) continue;
        if (pk3[(size_t)s * NTOK + t] <= thrk) { full = true; break; }  // >=3 in band
        if (nc == 8) { full = true; break; }
        xlist[t * 8 + nc++] = s * 64 + (int)(a & 63u);
        unsigned b = pk2[(size_t)s * NTOK + t];
        if (b <= thrk) {
            if (nc == 8) { full = true; break; }
            xlist[t * 8 + nc++] = s * 64 + (int)(b & 63u);
        }
    }
    if (full) {
        int q = atomicAdd(flagCount2, 1);
        flagList2[q] = t;
    } else {
        xn[t] = nc;
        int q = atomicAdd(flagCount, 1);
        flagList[q] = t;
    }
}

// ---------------- exact fp64 referee over candidate list ----------------
__global__ void k_tri(const float* __restrict__ z, const float* __restrict__ emb,
                      const double* __restrict__ enorm64,
                      const int* __restrict__ flagList, const int* __restrict__ flagCount,
                      const int* __restrict__ xlist, const int* __restrict__ xn,
                      int* __restrict__ idx32, int* __restrict__ cnt,
                      float* __restrict__ out_idx) {
    const int lane = threadIdx.x & 63;
    const int wid = blockIdx.x * (blockDim.x >> 6) + (threadIdx.x >> 6);
    const int nw = gridDim.x * (blockDim.x >> 6);
    const int nf = *flagCount;
    for (int f = wid; f < nf; f += nw) {
        int t = flagList[f];
        int b = t >> 12, x = t & 4095;
        double zz[4];
        #pragma unroll
        for (int u = 0; u < 4; ++u)
            zz[u] = (double)z[(size_t)(b * 256 + lane * 4 + u) * 4096 + x];
        int m = xn[t];
        double best = 1e300; int bi = IBIG;
        for (int c = 0; c < m; ++c) {
            int j = xlist[t * 8 + c];
            float4 e = ((const float4*)emb)[(size_t)j * 64 + lane];
            double d = zz[0] * (double)e.x + zz[1] * (double)e.y
                     + zz[2] * (double)e.z + zz[3] * (double)e.w;
            #pragma unroll
            for (int off = 32; off; off >>= 1) d += __shfl_down(d, off, 64);
            double s = enorm64[j] - 2.0 * d;   // valid on lane 0
            if (s < best || (s == best && j < bi)) { best = s; bi = j; }
        }
        if (lane == 0) {
            int old = idx32[t];
            if (bi != old) {
                idx32[t] = bi;
                out_idx[t] = (float)bi;
                atomicSub(&cnt[old], 1);
                atomicAdd(&cnt[bi], 1);
            }
        }
    }
}

// ---------------- fp64 full-row recheck (rare fallback) ----------------
__global__ void k_recheck(const float* __restrict__ z, const float* __restrict__ emb,
                          const double* __restrict__ enorm64,
                          const int* __restrict__ flagList, const int* __restrict__ flagCount,
                          int* __restrict__ idx32, int* __restrict__ cnt,
                          float* __restrict__ out_idx) {
    __shared__ float zrow[E_DIM];
    __shared__ double rv[1024];
    __shared__ int ri[1024];
    const int tid = threadIdx.x;
    const int nf = *flagCount;
    for (int f = blockIdx.x; f < nf; f += gridDim.x) {
        const int t = flagList[f];
        const int b = t >> 12, x = t & 4095;
        __syncthreads();
        if (tid < E_DIM) zrow[tid] = z[(size_t)(b * 256 + tid) * 4096 + x];
        __syncthreads();
        double best = 1e300; int bi = IBIG;
        for (int s = 0; s < N_E / 1024; s++) {
            int j = s * 1024 + tid;
            const float4* er4 = (const float4*)(emb + (size_t)j * E_DIM);
            double a0 = 0.0, a1 = 0.0, a2 = 0.0, a3 = 0.0;
            for (int k4 = 0; k4 < 64; ++k4) {
                float4 e = er4[k4];
                a0 = fma((double)e.x, (double)zrow[k4 * 4 + 0], a0);
                a1 = fma((double)e.y, (double)zrow[k4 * 4 + 1], a1);
                a2 = fma((double)e.z, (double)zrow[k4 * 4 + 2], a2);
                a3 = fma((double)e.w, (double)zrow[k4 * 4 + 3], a3);
            }
            double d = enorm64[j] - 2.0 * ((a0 + a1) + (a2 + a3));
            if (d < best || (d == best && j < bi)) { best = d; bi = j; }
        }
        rv[tid] = best; ri[tid] = bi;
        __syncthreads();
        for (int off = 512; off; off >>= 1) {
            if (tid < off) {
                if (rv[tid + off] < rv[tid] ||
                    (rv[tid + off] == rv[tid] && ri[tid + off] < ri[tid])) {
                    rv[tid] = rv[tid + off]; ri[tid] = ri[tid + off];
                }
            }
            __syncthreads();
        }
        if (tid == 0) {
            int old = idx32[t];
            int nw = ri[0];
            if (nw != old) {
                idx32[t] = nw;
                out_idx[t] = (float)nw;
                atomicSub(&cnt[old], 1);
                atomicAdd(&cnt[nw], 1);
            }
        }
        __syncthreads();
    }
}

// ---------------- exclusive scan of cnt[4096] + n/usage stats ----------------
__global__ void k_scan(const int* __restrict__ cnt, int* __restrict__ offs,
                       const float* __restrict__ cluster_size,
                       float* __restrict__ nval, float* __restrict__ out_usage) {
    __shared__ int sc[1024];
    __shared__ float sn[1024];
    __shared__ float su[1024];
    int tid = threadIdx.x;
    int c0 = cnt[tid * 4], c1 = cnt[tid * 4 + 1], c2 = cnt[tid * 4 + 2], c3 = cnt[tid * 4 + 3];
    int ls = c0 + c1 + c2 + c3;
    float ns = 0.f, us = 0.f;
    {
        int cc[4] = {c0, c1, c2, c3};
        #pragma unroll
        for (int u = 0; u < 4; ++u) {
            ns += cluster_size[tid * 4 + u] * DECAY + (1.f - DECAY) * (float)cc[u];
            us += (cc[u] > 0) ? 1.f : 0.f;
        }
    }
    sc[tid] = ls; sn[tid] = ns; su[tid] = us;
    __syncthreads();
    for (int off = 1; off < 1024; off <<= 1) {
        int v = (tid >= off) ? sc[tid - off] : 0;
        __syncthreads();
        sc[tid] += v;
        __syncthreads();
    }
    int base = sc[tid] - ls;
    offs[tid * 4] = base;
    offs[tid * 4 + 1] = base + c0;
    offs[tid * 4 + 2] = base + c0 + c1;
    offs[tid * 4 + 3] = base + c0 + c1 + c2;
    for (int off = 512; off; off >>= 1) {
        if (tid < off) { sn[tid] += sn[tid + off]; su[tid] += su[tid + off]; }
        __syncthreads();
    }
    if (tid == 0) { *nval = sn[0]; *out_usage = su[0] / (float)N_E; }
}

// ---------------- place tokens into per-code lists ----------------
__global__ void k_place(const int* __restrict__ idx32, int* __restrict__ offs,
                        int* __restrict__ tokList) {
    int t = blockIdx.x * blockDim.x + threadIdx.x;
    if (t >= NTOK) return;
    int j = idx32[t];
    int p = atomicAdd(&offs[j], 1);
    tokList[p] = t;
}

// ---------------- dw partials: (code, split) blocks, 8 lane-groups, pipelined ----------------
__global__ __launch_bounds__(512) void k_dw(const unsigned short* __restrict__ zh,
                       const int* __restrict__ cnt, const int* __restrict__ offs,
                       const int* __restrict__ tokList, float* __restrict__ dwp) {
    __shared__ float red[8][256];
    const int j = blockIdx.x;
    const int split = blockIdx.y;          // 0..NSPL-1
    const int g = threadIdx.x >> 6;        // 0..7
    const int lane = threadIdx.x & 63;
    const int n = cnt[j];
    const int s0 = offs[j] - n;            // offs holds end positions after k_place
    const int stride = NSPL * 8;           // 32
    float4 acc = make_float4(0.f, 0.f, 0.f, 0.f);
    int i = split * 8 + g;
    if (i < n) {
        int t_cur = tokList[s0 + i];
        i += stride;
        for (; i < n; i += stride) {
            int t_nxt = tokList[s0 + i];   // overlaps with zh gather below
            ushort4 h = *(const ushort4*)&zh[(size_t)t_cur * 256 + lane * 4];
            acc.x += h2f(h.x); acc.y += h2f(h.y);
            acc.z += h2f(h.z); acc.w += h2f(h.w);
            t_cur = t_nxt;
        }
        ushort4 h = *(const ushort4*)&zh[(size_t)t_cur * 256 + lane * 4];
        acc.x += h2f(h.x); acc.y += h2f(h.y);
        acc.z += h2f(h.z); acc.w += h2f(h.w);
    }
    red[g][lane * 4 + 0] = acc.x; red[g][lane * 4 + 1] = acc.y;
    red[g][lane * 4 + 2] = acc.z; red[g][lane * 4 + 3] = acc.w;
    __syncthreads();
    if (g == 0) {
        float4 o;
        int c = lane * 4;
        o.x = red[0][c+0] + red[1][c+0] + red[2][c+0] + red[3][c+0]
            + red[4][c+0] + red[5][c+0] + red[6][c+0] + red[7][c+0];
        o.y = red[0][c+1] + red[1][c+1] + red[2][c+1] + red[3][c+1]
            + red[4][c+1] + red[5][c+1] + red[6][c+1] + red[7][c+1];
        o.z = red[0][c+2] + red[1][c+2] + red[2][c+2] + red[3][c+2]
            + red[4][c+2] + red[5][c+2] + red[6][c+2] + red[7][c+2];
        o.w = red[0][c+3] + red[1][c+3] + red[2][c+3] + red[3][c+3]
            + red[4][c+3] + red[5][c+3] + red[6][c+3] + red[7][c+3];
        ((float4*)dwp)[((size_t)split * N_E + j) * 64 + lane] = o;
    }
}

// ---------------- final: sum split partials + EMA epilogue ----------------
__global__ void k_final(const float* __restrict__ dwp, const int* __restrict__ cnt,
                        const float* __restrict__ cluster_size,
                        const float* __restrict__ emb_avg, const float* __restrict__ nval,
                        float* __restrict__ out_cluster, float* __restrict__ out_avg,
                        float* __restrict__ out_embed) {
    int j = blockIdx.x * 4 + (threadIdx.x >> 6);
    int lane = threadIdx.x & 63;
    float4 dw = make_float4(0.f, 0.f, 0.f, 0.f);
    #pragma unroll
    for (int s = 0; s < NSPL; ++s) {
        float4 v = ((const float4*)dwp)[((size_t)s * N_E + j) * 64 + lane];
        dw.x += v.x; dw.y += v.y; dw.z += v.z; dw.w += v.w;
    }
    float nc = cluster_size[j] * DECAY + (1.f - DECAY) * (float)cnt[j];
    float nv = *nval;
    float cs = (nc + EPSV) / (nv + (float)N_E * EPSV) * nv;
    float4 ea = ((const float4*)emb_avg)[(size_t)j * 64 + lane];
    float4 na, ne;
    na.x = ea.x * DECAY + (1.f - DECAY) * dw.x;
    na.y = ea.y * DECAY + (1.f - DECAY) * dw.y;
    na.z = ea.z * DECAY + (1.f - DECAY) * dw.z;
    na.w = ea.w * DECAY + (1.f - DECAY) * dw.w;
    ne.x = na.x / cs; ne.y = na.y / cs; ne.z = na.z / cs; ne.w = na.w / cs;
    ((float4*)out_avg)[(size_t)j * 64 + lane] = na;
    ((float4*)out_embed)[(size_t)j * 64 + lane] = ne;
    if (lane == 0) out_cluster[j] = nc;
}

// ---------------- zq gather (vectorized: 4-token float4 writes) ----------------
__global__ void k_zq(const float* __restrict__ emb, const int* __restrict__ idx32,
                     float* __restrict__ out_zq) {
    int t0 = blockIdx.x * 16;            // 2048 blocks x 16 tokens
    int b = t0 >> 12, x0 = t0 & 4095;
    int c4 = threadIdx.x >> 2;           // 0..63
    int xq = threadIdx.x & 3;            // 0..3
    int jj[4];
    #pragma unroll
    for (int i = 0; i < 4; ++i) jj[i] = idx32[t0 + xq * 4 + i];
    float4 e[4];
    #pragma unroll
    for (int i = 0; i < 4; ++i)
        e[i] = ((const float4*)emb)[(size_t)jj[i] * 64 + c4];
    float* ob = out_zq + (size_t)b * (E_DIM * ZX) + x0 + xq * 4;
    {
        float4 v = make_float4(e[0].x, e[1].x, e[2].x, e[3].x);
        *(float4*)&ob[(size_t)(c4 * 4 + 0) * ZX] = v;
    }
    {
        float4 v = make_float4(e[0].y, e[1].y, e[2].y, e[3].y);
        *(float4*)&ob[(size_t)(c4 * 4 + 1) * ZX] = v;
    }
    {
        float4 v = make_float4(e[0].z, e[1].z, e[2].z, e[3].z);
        *(float4*)&ob[(size_t)(c4 * 4 + 2) * ZX] = v;
    }
    {
        float4 v = make_float4(e[0].w, e[1].w, e[2].w, e[3].w);
        *(float4*)&ob[(size_t)(c4 * 4 + 3) * ZX] = v;
    }
}

extern "C" void kernel_launch(void* const* d_in, const int* in_sizes, int n_in,
                              void* d_out, int out_size, void* d_ws, size_t ws_size,
                              hipStream_t stream) {
    const float* z            = (const float*)d_in[0];
    const float* emb          = (const float*)d_in[1];
    const float* cluster_size = (const float*)d_in[2];
    const float* emb_avg      = (const float*)d_in[3];
    float* out = (float*)d_out;

    // ---- d_ws layout (bytes), ~18.5 MB ----
    char* ws = (char*)d_ws;
    unsigned short* zh   = (unsigned short*)(ws + 0);          // 16,777,216 (f16)
    float* enorm32       = (float*)(ws + 16777216);            // 16,384
    double* enorm64      = (double*)(ws + 16793600);           // 32,768
    int* idx32           = (int*)(ws + 16826368);              // 131,072
    int* flagList        = (int*)(ws + 16957440);              // 131,072
    int* flagList2       = (int*)(ws + 17088512);              // 131,072
    int* xlist           = (int*)(ws + 17219584);              // 1,048,576
    int* xn              = (int*)(ws + 18268160);              // 131,072
    int* cnt             = (int*)(ws + 18399232);              // 16,384
    int* offs            = (int*)(ws + 18415616);              // 16,384
    int* flagCnt         = (int*)(ws + 18432000);              // 64
    int* flagCnt2        = (int*)(ws + 18432064);              // 64
    float* nval          = (float*)(ws + 18432128);            // 64

    // ---- scratch inside d_out's zq region (zq written last) ----
    unsigned* pk1        = (unsigned*)(out + 0);        // 8 MB
    unsigned* pk2        = (unsigned*)(out + 2097152);  // 8 MB
    unsigned* pk3        = (unsigned*)(out + 4194304);  // 8 MB
    float* dwp           = out + 0;                     // 16 MB, reuses pk1/pk2 (dead after k_merge)
    unsigned short* Bp   = (unsigned short*)(out + 7340032);   // 2 MB
    int*   tokList       = (int*)(out + 7864320);       // 128 KB (ends 7,897,088)

    // ---- output sections ----
    float* out_zq      = out + 0;
    float* out_idx     = out + 8388608;
    float* out_cluster = out + 8421376;
    float* out_avg     = out + 8425472;
    float* out_embed   = out + 9474048;
    float* out_usage   = out + 10522624;

    hipLaunchKernelGGL(k_prep_z, dim3(2048), dim3(256), 0, stream, z, zh);
    hipLaunchKernelGGL(k_prep_e, dim3(1024), dim3(256), 0, stream, emb, Bp, enorm32, enorm64,
                       cnt, flagCnt, flagCnt2);
    hipLaunchKernelGGL(k_dist,   dim3(256, NJB), dim3(256), 0, stream,
                       zh, Bp, enorm32, pk1, pk2, pk3);
    hipLaunchKernelGGL(k_merge,  dim3(128), dim3(256), 0, stream,
                       pk1, pk2, pk3, idx32, cnt, out_idx,
                       xlist, xn, flagList, flagCnt, flagList2, flagCnt2);
    hipLaunchKernelGGL(k_tri,    dim3(512), dim3(256), 0, stream,
                       z, emb, enorm64, flagList, flagCnt, xlist, xn, idx32, cnt, out_idx);
    hipLaunchKernelGGL(k_recheck, dim3(128), dim3(1024), 0, stream,
                       z, emb, enorm64, flagList2, flagCnt2, idx32, cnt, out_idx);
    hipLaunchKernelGGL(k_scan,   dim3(1), dim3(1024), 0, stream, cnt, offs,
                       cluster_size, nval, out_usage);
    hipLaunchKernelGGL(k_place,  dim3(128), dim3(256), 0, stream, idx32, offs, tokList);
    hipLaunchKernelGGL(k_dw,     dim3(4096, NSPL), dim3(512), 0, stream,
                       zh, cnt, offs, tokList, dwp);
    hipLaunchKernelGGL(k_final,  dim3(1024), dim3(256), 0, stream,
                       dwp, cnt, cluster_size, emb_avg, nval,
                       out_cluster, out_avg, out_embed);
    hipLaunchKernelGGL(k_zq,     dim3(2048), dim3(256), 0, stream, emb, idx32, out_zq);
}

// Round 11
// 199.793 us; speedup vs baseline: 4.3072x; 1.0098x over previous
//
#include <hip/hip_runtime.h>

#define N_E   4096
#define E_DIM 256
#define NTOK  32768
#define ZX    4096
#define DECAY 0.99f
#define EPSV  1e-5f
#define TAU   0.3f
#define NJB   32        // N_E / 128 j-blocks
#define NHALF 64        // 64-col halves
#define NSPL  4         // dw splits per code
#define IBIG  0x7fffffff

typedef _Float16 half8 __attribute__((ext_vector_type(8)));
typedef __attribute__((ext_vector_type(4))) float f32x4;

__device__ __forceinline__ unsigned short f2h(float x) {
    _Float16 h = (_Float16)x;
    unsigned short u;
    __builtin_memcpy(&u, &h, 2);
    return u;
}
__device__ __forceinline__ float h2f(unsigned short u) {
    _Float16 h;
    __builtin_memcpy(&h, &u, 2);
    return (float)h;
}
__device__ __forceinline__ unsigned umin2(unsigned a, unsigned b) { return a < b ? a : b; }
__device__ __forceinline__ unsigned umax2(unsigned a, unsigned b) { return a > b ? a : b; }
__device__ __forceinline__ void gload16(const void* g, void* l) {
    __builtin_amdgcn_global_load_lds(
        (const __attribute__((address_space(1))) char*)g,
        (__attribute__((address_space(3))) char*)l, 16, 0, 0);
}

// ---------------- fused prep: blocks <2048 do z->f16; rest do emb prep + init ----------------
__global__ void k_prep(const float* __restrict__ z, unsigned short* __restrict__ zh,
                       const float* __restrict__ emb, unsigned short* __restrict__ Bp,
                       float* __restrict__ enorm32, double* __restrict__ enorm64,
                       int* __restrict__ cnt, int* __restrict__ flagCnt,
                       int* __restrict__ flagCnt2) {
    __shared__ float lt[64][65];
    const int tid = threadIdx.x;
    if (blockIdx.x < 2048) {
        const int bid = blockIdx.x;
        const int xt = bid & 63, ct = (bid >> 6) & 3, b = bid >> 8;
        #pragma unroll
        for (int r = 0; r < 4; ++r) {
            int cy = r * 16 + (tid >> 4);
            int xx4 = tid & 15;
            float4 v = ((const float4*)z)[(size_t)(b * 256 + ct * 64 + cy) * 1024 + xt * 16 + xx4];
            lt[cy][xx4 * 4 + 0] = v.x; lt[cy][xx4 * 4 + 1] = v.y;
            lt[cy][xx4 * 4 + 2] = v.z; lt[cy][xx4 * 4 + 3] = v.w;
        }
        __syncthreads();
        #pragma unroll
        for (int it = 0; it < 2; ++it) {
            int tl = it * 32 + (tid >> 3);
            int c8 = tid & 7;
            unsigned short h[8];
            #pragma unroll
            for (int u = 0; u < 8; ++u) h[u] = f2h(lt[c8 * 8 + u][tl]);
            size_t t = (size_t)(b * 4096 + xt * 64 + tl);
            size_t o = t * 256 + ct * 64 + c8 * 8;
            *(ushort4*)&zh[o]     = make_ushort4(h[0], h[1], h[2], h[3]);
            *(ushort4*)&zh[o + 4] = make_ushort4(h[4], h[5], h[6], h[7]);
        }
    } else {
        const int eb = blockIdx.x - 2048;
        if (tid < 4) cnt[eb * 4 + tid] = 0;
        if (eb == 0 && tid == 0) { *flagCnt = 0; *flagCnt2 = 0; }
        int j = eb * 4 + (tid >> 6);
        int lane = tid & 63;
        float4 v = ((const float4*)emb)[(size_t)j * 64 + lane];
        float f[4] = {v.x, v.y, v.z, v.w};
        unsigned short h[4];
        #pragma unroll
        for (int u = 0; u < 4; ++u) h[u] = f2h(f[u]);
        *(ushort4*)&Bp[(size_t)j * E_DIM + lane * 4] = make_ushort4(h[0], h[1], h[2], h[3]);
        double s = 0.0;
        #pragma unroll
        for (int u = 0; u < 4; ++u) s += (double)f[u] * (double)f[u];
        #pragma unroll
        for (int off = 32; off; off >>= 1) s += __shfl_down(s, off, 64);
        if (lane == 0) { enorm32[j] = (float)s; enorm64[j] = s; }
    }
}

// ---------------- MFMA f16 distance; per-half top-3 packed keys (single-buffer) ----------------
__global__ __launch_bounds__(256) void k_dist(
        const unsigned short* __restrict__ zh,
        const unsigned short* __restrict__ Bp, const float* __restrict__ enorm32,
        unsigned* __restrict__ pk1, unsigned* __restrict__ pk2, unsigned* __restrict__ pk3) {
    __shared__ __align__(16) char smem[32768];   // single buffer: 16KB A + 16KB B
    const int tid = threadIdx.x;
    const int lane = tid & 63;
    const int w = tid >> 6;
    const int wr = w >> 1, wc = w & 1;
    const int t0 = blockIdx.x * 128;
    const int jb = blockIdx.y;
    const int j0 = jb * 128;
    const int sw16 = (((lane & 7) ^ (lane >> 3)) << 4);
    const int rowsub = lane >> 3;

    f32x4 acc[4][4];
    #pragma unroll
    for (int m = 0; m < 4; ++m)
        #pragma unroll
        for (int nn = 0; nn < 4; ++nn)
            acc[m][nn] = (f32x4){0.f, 0.f, 0.f, 0.f};

    auto stage = [&](int s) {
        const int kb = s * 128 + sw16;
        #pragma unroll
        for (int c = 0; c < 4; ++c) {
            int seg = w * 4 + c;
            int arow = t0 + seg * 8 + rowsub;
            int brow = j0 + seg * 8 + rowsub;
            gload16((const char*)zh + (size_t)arow * 512 + kb, &smem[seg * 1024]);
            gload16((const char*)Bp + (size_t)brow * 512 + kb, &smem[16384 + seg * 1024]);
        }
    };

    stage(0);
    for (int s = 0; s < 4; ++s) {
        __syncthreads();                 // staged data visible (vmcnt drained)
        const int xr = ((lane & 7) << 4);
        #pragma unroll
        for (int kk = 0; kk < 2; ++kk) {
            const int colb = (kk * 64 + ((lane >> 4) << 4)) ^ xr;
            half8 a[4], b[4];
            #pragma unroll
            for (int m = 0; m < 4; ++m)
                a[m] = *(const half8*)&smem[((wr * 64 + m * 16 + (lane & 15)) << 7) + colb];
            #pragma unroll
            for (int nn = 0; nn < 4; ++nn)
                b[nn] = *(const half8*)&smem[16384 + ((wc * 64 + nn * 16 + (lane & 15)) << 7) + colb];
            // swapped operands: D[row=code, col=token]
            #pragma unroll
            for (int m = 0; m < 4; ++m)
                #pragma unroll
                for (int nn = 0; nn < 4; ++nn)
                    acc[m][nn] = __builtin_amdgcn_mfma_f32_16x16x32_f16(b[nn], a[m], acc[m][nn], 0, 0, 0);
        }
        if (s < 3) {
            __syncthreads();             // all waves done reading -> safe to overwrite
            stage(s + 1);
        }
    }

    // ---- epilogue: per-half top-3 packed u32 keys; 2-pass butterfly ----
    const int g   = lane >> 4;       // code row-group
    const int gg4 = g * 4;
    const int h   = jb * 2 + wc;
    float enb[4][4];
    #pragma unroll
    for (int nn = 0; nn < 4; ++nn) {
        float4 e4 = *(const float4*)&enorm32[j0 + wc * 64 + nn * 16 + gg4];
        enb[nn][0] = e4.x + 4096.f; enb[nn][1] = e4.y + 4096.f;
        enb[nn][2] = e4.z + 4096.f; enb[nn][3] = e4.w + 4096.f;
    }
    unsigned s1 = 0, s2 = 0, s3 = 0;
    #pragma unroll
    for (int m = 0; m < 4; ++m) {
        unsigned k1 = 0xFFFFFFFFu, k2 = 0xFFFFFFFFu, k3 = 0xFFFFFFFFu;
        #pragma unroll
        for (int nn = 0; nn < 4; ++nn)
            #pragma unroll
            for (int r = 0; r < 4; ++r) {
                float sc = fmaf(-2.f, acc[m][nn][r], enb[nn][r]);   // > 0 by construction
                unsigned key = (__float_as_uint(sc) & 0xFFFFFFC0u)
                             | (unsigned)(gg4 + nn * 16 + r);
                k3 = umin2(k3, umax2(k2, key));
                k2 = umin2(k2, umax2(k1, key));
                k1 = umin2(k1, key);
            }
        #pragma unroll
        for (int off = 16; off <= 32; off <<= 1) {
            unsigned b1 = (unsigned)__shfl_xor((int)k1, off, 64);
            unsigned b2 = (unsigned)__shfl_xor((int)k2, off, 64);
            unsigned b3 = (unsigned)__shfl_xor((int)k3, off, 64);
            unsigned p  = umax2(k1, b1);
            unsigned q  = umin2(k2, b2);
            unsigned r2 = umax2(k2, b2);
            unsigned ss = umin2(k3, b3);
            k1 = umin2(k1, b1);
            k2 = umin2(p, q);
            k3 = umin2(umax2(p, q), umin2(r2, ss));
        }
        s1 = (g == m) ? k1 : s1;
        s2 = (g == m) ? k2 : s2;
        s3 = (g == m) ? k3 : s3;
    }
    size_t o = (size_t)h * NTOK + t0 + wr * 64 + lane;
    pk1[o] = s1; pk2[o] = s2; pk3[o] = s3;
}

// ---------------- merge halves on keys, histogram, candidate collection ----------------
__global__ void k_merge(const unsigned* __restrict__ pk1, const unsigned* __restrict__ pk2,
                        const unsigned* __restrict__ pk3,
                        int* __restrict__ idx32, int* __restrict__ cnt,
                        float* __restrict__ out_idx,
                        int* __restrict__ xlist, int* __restrict__ xn,
                        int* __restrict__ flagList, int* __restrict__ flagCount,
                        int* __restrict__ flagList2, int* __restrict__ flagCount2) {
    int t = blockIdx.x * blockDim.x + threadIdx.x;
    if (t >= NTOK) return;
    unsigned g1 = 0xFFFFFFFFu, g2 = 0xFFFFFFFFu;
    int h1 = 0;
    #pragma unroll 4
    for (int s = 0; s < NHALF; s++) {
        unsigned a = pk1[(size_t)s * NTOK + t];
        unsigned b = pk2[(size_t)s * NTOK + t];
        bool c = a < g1;
        g2 = c ? g1 : umin2(g2, a);
        h1 = c ? s : h1;
        g1 = c ? a : g1;
        g2 = umin2(g2, b);          // b >= a so never the global min
    }
    int x1 = h1 * 64 + (int)(g1 & 63u);
    idx32[t] = x1;
    atomicAdd(&cnt[x1], 1);
    out_idx[t] = (float)x1;
    float v1 = __uint_as_float(g1 & 0xFFFFFFC0u);
    float v2 = __uint_as_float(g2 & 0xFFFFFFC0u);
    if (v2 - v1 >= TAU) return;     // winner certain at fp16 precision
    unsigned thrk = __float_as_uint(v1 + TAU) | 63u;
    int nc = 0; bool full = false;
    for (int s = 0; s < NHALF; s++) {
        unsigned a = pk1[(size_t)s * NTOK + t];
        if (a > thrk) continue;
        if (pk3[(size_t)s * NTOK + t] <= thrk) { full = true; break; }  // >=3 in band
        if (nc == 8) { full = true; break; }
        xlist[t * 8 + nc++] = s * 64 + (int)(a & 63u);
        unsigned b = pk2[(size_t)s * NTOK + t];
        if (b <= thrk) {
            if (nc == 8) { full = true; break; }
            xlist[t * 8 + nc++] = s * 64 + (int)(b & 63u);
        }
    }
    if (full) {
        int q = atomicAdd(flagCount2, 1);
        flagList2[q] = t;
    } else {
        xn[t] = nc;
        int q = atomicAdd(flagCount, 1);
        flagList[q] = t;
    }
}

// ---------------- fused referee: blocks<384 tri (candidate lists), rest full recheck ----------------
__global__ __launch_bounds__(512) void k_triR(
        const float* __restrict__ z, const float* __restrict__ emb,
        const double* __restrict__ enorm64,
        const int* __restrict__ flagList, const int* __restrict__ flagCount,
        const int* __restrict__ xlist, const int* __restrict__ xn,
        const int* __restrict__ flagList2, const int* __restrict__ flagCount2,
        int* __restrict__ idx32, int* __restrict__ cnt, float* __restrict__ out_idx) {
    __shared__ float zrow[E_DIM];
    __shared__ double rv[512];
    __shared__ int ri[512];
    const int tid = threadIdx.x;
    if (blockIdx.x < 384) {
        // ---- tri role: exact fp64 over <=8 candidates, one wave per token ----
        const int lane = tid & 63;
        const int wid = blockIdx.x * 8 + (tid >> 6);
        const int nw = 384 * 8;
        const int nf = *flagCount;
        for (int f = wid; f < nf; f += nw) {
            int t = flagList[f];
            int b = t >> 12, x = t & 4095;
            double zz[4];
            #pragma unroll
            for (int u = 0; u < 4; ++u)
                zz[u] = (double)z[(size_t)(b * 256 + lane * 4 + u) * 4096 + x];
            int m = xn[t];
            double best = 1e300; int bi = IBIG;
            for (int c = 0; c < m; ++c) {
                int j = xlist[t * 8 + c];
                float4 e = ((const float4*)emb)[(size_t)j * 64 + lane];
                double d = zz[0] * (double)e.x + zz[1] * (double)e.y
                         + zz[2] * (double)e.z + zz[3] * (double)e.w;
                #pragma unroll
                for (int off = 32; off; off >>= 1) d += __shfl_down(d, off, 64);
                double s = enorm64[j] - 2.0 * d;   // valid on lane 0
                if (s < best || (s == best && j < bi)) { best = s; bi = j; }
            }
            if (lane == 0) {
                int old = idx32[t];
                if (bi != old) {
                    idx32[t] = bi;
                    out_idx[t] = (float)bi;
                    atomicSub(&cnt[old], 1);
                    atomicAdd(&cnt[bi], 1);
                }
            }
        }
    } else {
        // ---- recheck role: full fp64 row scan ----
        const int nf = *flagCount2;
        for (int f = blockIdx.x - 384; f < nf; f += 128) {
            const int t = flagList2[f];
            const int b = t >> 12, x = t & 4095;
            __syncthreads();
            if (tid < E_DIM) zrow[tid] = z[(size_t)(b * 256 + tid) * 4096 + x];
            __syncthreads();
            double best = 1e300; int bi = IBIG;
            for (int s = 0; s < N_E / 512; s++) {
                int j = s * 512 + tid;
                const float4* er4 = (const float4*)(emb + (size_t)j * E_DIM);
                double a0 = 0.0, a1 = 0.0, a2 = 0.0, a3 = 0.0;
                for (int k4 = 0; k4 < 64; ++k4) {
                    float4 e = er4[k4];
                    a0 = fma((double)e.x, (double)zrow[k4 * 4 + 0], a0);
                    a1 = fma((double)e.y, (double)zrow[k4 * 4 + 1], a1);
                    a2 = fma((double)e.z, (double)zrow[k4 * 4 + 2], a2);
                    a3 = fma((double)e.w, (double)zrow[k4 * 4 + 3], a3);
                }
                double d = enorm64[j] - 2.0 * ((a0 + a1) + (a2 + a3));
                if (d < best || (d == best && j < bi)) { best = d; bi = j; }
            }
            rv[tid] = best; ri[tid] = bi;
            __syncthreads();
            for (int off = 256; off; off >>= 1) {
                if (tid < off) {
                    if (rv[tid + off] < rv[tid] ||
                        (rv[tid + off] == rv[tid] && ri[tid + off] < ri[tid])) {
                        rv[tid] = rv[tid + off]; ri[tid] = ri[tid + off];
                    }
                }
                __syncthreads();
            }
            if (tid == 0) {
                int old = idx32[t];
                int nw2 = ri[0];
                if (nw2 != old) {
                    idx32[t] = nw2;
                    out_idx[t] = (float)nw2;
                    atomicSub(&cnt[old], 1);
                    atomicAdd(&cnt[nw2], 1);
                }
            }
            __syncthreads();
        }
    }
}

// ---------------- exclusive scan of cnt[4096] + n/usage stats ----------------
__global__ void k_scan(const int* __restrict__ cnt, int* __restrict__ offs,
                       const float* __restrict__ cluster_size,
                       float* __restrict__ nval, float* __restrict__ out_usage) {
    __shared__ int sc[1024];
    __shared__ float sn[1024];
    __shared__ float su[1024];
    int tid = threadIdx.x;
    int c0 = cnt[tid * 4], c1 = cnt[tid * 4 + 1], c2 = cnt[tid * 4 + 2], c3 = cnt[tid * 4 + 3];
    int ls = c0 + c1 + c2 + c3;
    float ns = 0.f, us = 0.f;
    {
        int cc[4] = {c0, c1, c2, c3};
        #pragma unroll
        for (int u = 0; u < 4; ++u) {
            ns += cluster_size[tid * 4 + u] * DECAY + (1.f - DECAY) * (float)cc[u];
            us += (cc[u] > 0) ? 1.f : 0.f;
        }
    }
    sc[tid] = ls; sn[tid] = ns; su[tid] = us;
    __syncthreads();
    for (int off = 1; off < 1024; off <<= 1) {
        int v = (tid >= off) ? sc[tid - off] : 0;
        __syncthreads();
        sc[tid] += v;
        __syncthreads();
    }
    int base = sc[tid] - ls;
    offs[tid * 4] = base;
    offs[tid * 4 + 1] = base + c0;
    offs[tid * 4 + 2] = base + c0 + c1;
    offs[tid * 4 + 3] = base + c0 + c1 + c2;
    for (int off = 512; off; off >>= 1) {
        if (tid < off) { sn[tid] += sn[tid + off]; su[tid] += su[tid + off]; }
        __syncthreads();
    }
    if (tid == 0) { *nval = sn[0]; *out_usage = su[0] / (float)N_E; }
}

// ---------------- place tokens into per-code lists ----------------
__global__ void k_place(const int* __restrict__ idx32, int* __restrict__ offs,
                        int* __restrict__ tokList) {
    int t = blockIdx.x * blockDim.x + threadIdx.x;
    if (t >= NTOK) return;
    int j = idx32[t];
    int p = atomicAdd(&offs[j], 1);
    tokList[p] = t;
}

// ---------------- dw partials: (code, split) blocks, 8 lane-groups, pipelined ----------------
__global__ __launch_bounds__(512) void k_dw(const unsigned short* __restrict__ zh,
                       const int* __restrict__ cnt, const int* __restrict__ offs,
                       const int* __restrict__ tokList, float* __restrict__ dwp) {
    __shared__ float red[8][256];
    const int j = blockIdx.x;
    const int split = blockIdx.y;          // 0..NSPL-1
    const int g = threadIdx.x >> 6;        // 0..7
    const int lane = threadIdx.x & 63;
    const int n = cnt[j];
    const int s0 = offs[j] - n;            // offs holds end positions after k_place
    const int stride = NSPL * 8;           // 32
    float4 acc = make_float4(0.f, 0.f, 0.f, 0.f);
    int i = split * 8 + g;
    if (i < n) {
        int t_cur = tokList[s0 + i];
        i += stride;
        for (; i < n; i += stride) {
            int t_nxt = tokList[s0 + i];   // overlaps with zh gather below
            ushort4 h = *(const ushort4*)&zh[(size_t)t_cur * 256 + lane * 4];
            acc.x += h2f(h.x); acc.y += h2f(h.y);
            acc.z += h2f(h.z); acc.w += h2f(h.w);
            t_cur = t_nxt;
        }
        ushort4 h = *(const ushort4*)&zh[(size_t)t_cur * 256 + lane * 4];
        acc.x += h2f(h.x); acc.y += h2f(h.y);
        acc.z += h2f(h.z); acc.w += h2f(h.w);
    }
    red[g][lane * 4 + 0] = acc.x; red[g][lane * 4 + 1] = acc.y;
    red[g][lane * 4 + 2] = acc.z; red[g][lane * 4 + 3] = acc.w;
    __syncthreads();
    if (g == 0) {
        float4 o;
        int c = lane * 4;
        o.x = red[0][c+0] + red[1][c+0] + red[2][c+0] + red[3][c+0]
            + red[4][c+0] + red[5][c+0] + red[6][c+0] + red[7][c+0];
        o.y = red[0][c+1] + red[1][c+1] + red[2][c+1] + red[3][c+1]
            + red[4][c+1] + red[5][c+1] + red[6][c+1] + red[7][c+1];
        o.z = red[0][c+2] + red[1][c+2] + red[2][c+2] + red[3][c+2]
            + red[4][c+2] + red[5][c+2] + red[6][c+2] + red[7][c+2];
        o.w = red[0][c+3] + red[1][c+3] + red[2][c+3] + red[3][c+3]
            + red[4][c+3] + red[5][c+3] + red[6][c+3] + red[7][c+3];
        ((float4*)dwp)[((size_t)split * N_E + j) * 64 + lane] = o;
    }
}

// ---------------- fused: blocks<1024 EMA epilogue; rest zq gather ----------------
__global__ void k_finalzq(const float* __restrict__ dwp, const int* __restrict__ cnt,
                          const float* __restrict__ cluster_size,
                          const float* __restrict__ emb_avg, const float* __restrict__ nval,
                          float* __restrict__ out_cluster, float* __restrict__ out_avg,
                          float* __restrict__ out_embed,
                          const float* __restrict__ emb, const int* __restrict__ idx32,
                          float* __restrict__ out_zq) {
    if (blockIdx.x < 1024) {
        int j = blockIdx.x * 4 + (threadIdx.x >> 6);
        int lane = threadIdx.x & 63;
        float4 dw = make_float4(0.f, 0.f, 0.f, 0.f);
        #pragma unroll
        for (int s = 0; s < NSPL; ++s) {
            float4 v = ((const float4*)dwp)[((size_t)s * N_E + j) * 64 + lane];
            dw.x += v.x; dw.y += v.y; dw.z += v.z; dw.w += v.w;
        }
        float nc = cluster_size[j] * DECAY + (1.f - DECAY) * (float)cnt[j];
        float nv = *nval;
        float cs = (nc + EPSV) / (nv + (float)N_E * EPSV) * nv;
        float4 ea = ((const float4*)emb_avg)[(size_t)j * 64 + lane];
        float4 na, ne;
        na.x = ea.x * DECAY + (1.f - DECAY) * dw.x;
        na.y = ea.y * DECAY + (1.f - DECAY) * dw.y;
        na.z = ea.z * DECAY + (1.f - DECAY) * dw.z;
        na.w = ea.w * DECAY + (1.f - DECAY) * dw.w;
        ne.x = na.x / cs; ne.y = na.y / cs; ne.z = na.z / cs; ne.w = na.w / cs;
        ((float4*)out_avg)[(size_t)j * 64 + lane] = na;
        ((float4*)out_embed)[(size_t)j * 64 + lane] = ne;
        if (lane == 0) out_cluster[j] = nc;
    } else {
        // zq: thread-per-token, scalar stores -> 256B-contiguous per wave-store
        int t = (blockIdx.x - 1024) * 256 + threadIdx.x;
        int j = idx32[t];
        int b = t >> 12, x = t & 4095;
        const float4* er = (const float4*)(emb + (size_t)j * E_DIM);
        float* ob = out_zq + (size_t)b * (E_DIM * ZX) + x;
        #pragma unroll 8
        for (int c4 = 0; c4 < E_DIM / 4; c4++) {
            float4 v = er[c4];
            ob[(size_t)(c4 * 4 + 0) * ZX] = v.x;
            ob[(size_t)(c4 * 4 + 1) * ZX] = v.y;
            ob[(size_t)(c4 * 4 + 2) * ZX] = v.z;
            ob[(size_t)(c4 * 4 + 3) * ZX] = v.w;
        }
    }
}

extern "C" void kernel_launch(void* const* d_in, const int* in_sizes, int n_in,
                              void* d_out, int out_size, void* d_ws, size_t ws_size,
                              hipStream_t stream) {
    const float* z            = (const float*)d_in[0];
    const float* emb          = (const float*)d_in[1];
    const float* cluster_size = (const float*)d_in[2];
    const float* emb_avg      = (const float*)d_in[3];
    float* out = (float*)d_out;

    // ---- d_ws layout (bytes), ~35.7 MB (R1 used 39.6 MB safely) ----
    char* ws = (char*)d_ws;
    unsigned short* zh   = (unsigned short*)(ws + 0);          // 16,777,216 (f16)
    float* enorm32       = (float*)(ws + 16777216);            // 16,384
    double* enorm64      = (double*)(ws + 16793600);           // 32,768
    int* idx32           = (int*)(ws + 16826368);              // 131,072
    int* flagList        = (int*)(ws + 16957440);              // 131,072
    int* flagList2       = (int*)(ws + 17088512);              // 131,072
    int* xlist           = (int*)(ws + 17219584);              // 1,048,576
    int* xn              = (int*)(ws + 18268160);              // 131,072
    int* cnt             = (int*)(ws + 18399232);              // 16,384
    int* offs            = (int*)(ws + 18415616);              // 16,384
    int* flagCnt         = (int*)(ws + 18432000);              // 64
    int* flagCnt2        = (int*)(ws + 18432064);              // 64
    float* nval          = (float*)(ws + 18432128);            // 64
    float* dwp           = (float*)(ws + 18874368);            // 16,777,216 (NSPL partials)

    // ---- scratch inside d_out's zq region (pk dead after k_merge; zq written last) ----
    unsigned* pk1        = (unsigned*)(out + 0);        // 8 MB
    unsigned* pk2        = (unsigned*)(out + 2097152);  // 8 MB
    unsigned* pk3        = (unsigned*)(out + 4194304);  // 8 MB
    unsigned short* Bp   = (unsigned short*)(out + 7340032);   // 2 MB
    int*   tokList       = (int*)(out + 7864320);       // 128 KB (ends 7,897,088)

    // ---- output sections ----
    float* out_zq      = out + 0;
    float* out_idx     = out + 8388608;
    float* out_cluster = out + 8421376;
    float* out_avg     = out + 8425472;
    float* out_embed   = out + 9474048;
    float* out_usage   = out + 10522624;

    hipLaunchKernelGGL(k_prep,   dim3(3072), dim3(256), 0, stream,
                       z, zh, emb, Bp, enorm32, enorm64, cnt, flagCnt, flagCnt2);
    hipLaunchKernelGGL(k_dist,   dim3(256, NJB), dim3(256), 0, stream,
                       zh, Bp, enorm32, pk1, pk2, pk3);
    hipLaunchKernelGGL(k_merge,  dim3(128), dim3(256), 0, stream,
                       pk1, pk2, pk3, idx32, cnt, out_idx,
                       xlist, xn, flagList, flagCnt, flagList2, flagCnt2);
    hipLaunchKernelGGL(k_triR,   dim3(512), dim3(512), 0, stream,
                       z, emb, enorm64, flagList, flagCnt, xlist, xn,
                       flagList2, flagCnt2, idx32, cnt, out_idx);
    hipLaunchKernelGGL(k_scan,   dim3(1), dim3(1024), 0, stream, cnt, offs,
                       cluster_size, nval, out_usage);
    hipLaunchKernelGGL(k_place,  dim3(128), dim3(256), 0, stream, idx32, offs, tokList);
    hipLaunchKernelGGL(k_dw,     dim3(4096, NSPL), dim3(512), 0, stream,
                       zh, cnt, offs, tokList, dwp);
    hipLaunchKernelGGL(k_finalzq, dim3(1152), dim3(256), 0, stream,
                       dwp, cnt, cluster_size, emb_avg, nval,
                       out_cluster, out_avg, out_embed, emb, idx32, out_zq);
}